// Round 11
// baseline (425.395 us; speedup 1.0000x reference)
//
#include <hip/hip_runtime.h>

typedef float  f4   __attribute__((ext_vector_type(4)));
typedef __bf16 bf8_t __attribute__((ext_vector_type(8)));
typedef __bf16 bf4_t __attribute__((ext_vector_type(4)));

__device__ __forceinline__ void glds16(const void* g, void* l) {
    __builtin_amdgcn_global_load_lds(
        (const __attribute__((address_space(1))) void*)g,
        (__attribute__((address_space(3))) void*)l, 16, 0, 0);
}

// ---------------------------------------------------------------------------
// prep: weight transposes (blocks 0..5279) + pos encodings / combined bias /
// rs2 zero (blocks 5280..6436).
// ---------------------------------------------------------------------------
__global__ __launch_bounds__(256)
void prep_kernel(float* __restrict__ P1, float* __restrict__ P2,
                 float* __restrict__ P3,
                 const float* __restrict__ bp1, const float* __restrict__ bp2,
                 float* __restrict__ bc, float* __restrict__ rs2,
                 const float* __restrict__ Wemb, __bf16* __restrict__ WembT,
                 const float* __restrict__ Wd2, __bf16* __restrict__ Wd2T,
                 const float* __restrict__ Wq1, __bf16* __restrict__ Wq1T,
                 const float* __restrict__ Wq2, __bf16* __restrict__ Wq2T,
                 const float* __restrict__ Wq3, __bf16* __restrict__ Wq3T) {
    const int bid = blockIdx.x;
    const int t = threadIdx.x;
    if (bid < 5280) {
        const float* src; __bf16* dst; int CN, RK, tn, local;
        if (bid < 4000)      { src = Wemb; dst = WembT; RK = 32000; CN = 128; tn = 4;  local = bid; }
        else if (bid < 4320) { src = Wd2;  dst = Wd2T;  RK = 640;   CN = 512; tn = 16; local = bid - 4000; }
        else if (bid < 4352) { src = Wq1;  dst = Wq1T;  RK = 256;   CN = 128; tn = 4;  local = bid - 4320; }
        else if (bid < 4480) { src = Wq2;  dst = Wq2T;  RK = 512;   CN = 256; tn = 8;  local = bid - 4352; }
        else                 { src = Wq3;  dst = Wq3T;  RK = 1280;  CN = 640; tn = 20; local = bid - 4480; }
        const int kt = local / tn, ntl = local - kt * tn;
        const int k0 = kt * 32, n0 = ntl * 32;
        __shared__ float tile[32][33];
        const int r = t >> 3, c4 = (t & 7) * 4;
        const f4 v = *(const f4*)(src + (long)(k0 + r) * CN + n0 + c4);
        tile[r][c4] = v[0]; tile[r][c4 + 1] = v[1];
        tile[r][c4 + 2] = v[2]; tile[r][c4 + 3] = v[3];
        __syncthreads();
        bf4_t o2;
        o2[0] = (__bf16)tile[c4][r];     o2[1] = (__bf16)tile[c4 + 1][r];
        o2[2] = (__bf16)tile[c4 + 2][r]; o2[3] = (__bf16)tile[c4 + 3][r];
        *(bf4_t*)(dst + (long)(n0 + r) * RK + k0 + c4) = o2;
        return;
    }
    int idx = (bid - 5280) * 256 + t;
    const int n1 = 128 * 256, n2 = 128 * 512;      // P3: 128*1280
    const int nP = 262144;
    if (idx < nP) {
        float* P; int d, local;
        if (idx < n1)           { P = P1; d = 256;  local = idx; }
        else if (idx < n1 + n2) { P = P2; d = 512;  local = idx - n1; }
        else                    { P = P3; d = 1280; local = idx - n1 - n2; }
        int s = local / d;
        int k = local - s * d;
        int i = k >> 1;
        float ang = (float)s * powf(10000.0f, (-2.0f * (float)i) / (float)d);
        P[local] = (k & 1) ? cosf(ang) : sinf(ang);
    } else if (idx < nP + 32000) {
        int j = idx - nP;
        bc[j] = 2.f * bp1[j] + bp2[j];
    } else if (idx < nP + 32000 + 2048) {
        rs2[idx - nP - 32000] = 0.f;
    }
}

// ---------------------------------------------------------------------------
// Core MFMA GEMM device body — exact R6 proven loop:
//   STAGE(next buf) | COMPUTE(cur) | __syncthreads.
//   BMODE 0: B = bf16 [N][K] pre-transposed; BMODE 1: B = fp32 [K][N] natural
//            (optional B2 switch at k >= kswitch, same ldb).
//   rsum != nullptr (ksplit==1): atomic row-sum accumulation (pre-zeroed).
// ---------------------------------------------------------------------------
template<int BMODE>
__device__ __forceinline__ void gemm_dev(
    float* As0, float* As1, float* Bb0, float* Bb1,
    const float* __restrict__ A, const void* __restrict__ Bv,
    const void* __restrict__ B2v, float* __restrict__ C,
    const float* __restrict__ bias, const float* __restrict__ addsrc,
    float* __restrict__ rsum,
    int M, int N, int K, int lda, int ldb, int ldc, int kswitch,
    long sA, long sB, long sC, int ksplit, int kchunk, int relu,
    int bn, int bm, int bz) {

    const int t = threadIdx.x;
    const int batch = bz / ksplit;
    const int kz = bz - batch * ksplit;
    const int m0 = bm * 64, n0 = bn * 128;
    const int kb = kz * kchunk;
    const int ke = (kb + kchunk < K) ? (kb + kchunk) : K;
    const int nit = (ke - kb + 31) >> 5;

    const int lane = t & 63;
    const int w = t >> 6;
    const int wm = w >> 1, wn = w & 1;
    const int fr = lane & 15;
    const int fq = (lane >> 4) * 8;

    f4 acc[2][4];
#pragma unroll
    for (int mt = 0; mt < 2; ++mt)
#pragma unroll
        for (int nt = 0; nt < 4; ++nt) acc[mt][nt] = (f4){0.f, 0.f, 0.f, 0.f};

    const float* Ab = A + (long)batch * sA;
    const int mvalid = M - m0;

    const int ra = t >> 3;
    const int ja = (t & 7) ^ (ra & 7);
    const float* aS0 = Ab + (long)(m0 + ra) * lda + 4 * ja;
    const float* aS1 = aS0 + 32L * lda;

    const __bf16* bTS0 = nullptr; const __bf16* bTS1 = nullptr;
    const float* bNS0 = nullptr; const float* bNS2 = nullptr;
    if constexpr (BMODE == 0) {
        const __bf16* BT = (const __bf16*)Bv + (long)batch * sB;
        const int nb = t >> 2;
        const int fb = (nb & 3) ^ ((nb >> 2) & 3);
        const int jb = (t & 3) ^ fb;
        bTS0 = BT + (long)(n0 + nb) * ldb + 8 * jb;
        bTS1 = bTS0 + 64L * ldb;
    } else {
        const float* Bn = (const float*)Bv + (long)batch * sB;
        bNS0 = Bn + (long)(t >> 5) * ldb + n0 + (t & 31) * 4;
        const float* Bn2 = (const float*)(B2v ? B2v : Bv);
        bNS2 = Bn2 + (long)(t >> 5) * ldb + n0 + (t & 31) * 4;
    }

    auto STAGE = [&](float* Ad, float* Bd, int k0) {
        if (ra < mvalid)      glds16(aS0 + k0, Ad + 4 * t);
        if (ra + 32 < mvalid) glds16(aS1 + k0, Ad + 1024 + 4 * t);
        if constexpr (BMODE == 0) {
            glds16(bTS0 + k0, Bd + 4 * t);
            glds16(bTS1 + k0, Bd + 1024 + 4 * t);
        } else {
            const float* bp = (k0 < kswitch) ? (bNS0 + (long)k0 * ldb)
                                             : (bNS2 + (long)(k0 - kswitch) * ldb);
            glds16(bp,             Bd + 4 * t);
            glds16(bp + 8L * ldb,  Bd + 1024 + 4 * t);
            glds16(bp + 16L * ldb, Bd + 2048 + 4 * t);
            glds16(bp + 24L * ldb, Bd + 3072 + 4 * t);
        }
    };

    // frag-read offsets (constant across K)
    const int R0 = wm * 32 + fr, R1 = R0 + 16;
    const int jq = (lane >> 4) * 2;
    const int x7 = R0 & 7;
    const int aO00 = R0 * 8 + (jq ^ x7);
    const int aO01 = R0 * 8 + ((jq + 1) ^ x7);
    const int aO10 = R1 * 8 + (jq ^ x7);
    const int aO11 = R1 * 8 + ((jq + 1) ^ x7);
    int bOf[4];
    if constexpr (BMODE == 0) {
        const int fbc = (fr & 3) ^ ((fr >> 2) & 3);
        const int jb2 = (lane >> 4) ^ fbc;
#pragma unroll
        for (int nt = 0; nt < 4; ++nt)
            bOf[nt] = ((wn * 64 + nt * 16 + fr) * 4 + jb2) * 8;  // bf16 idx
    } else {
#pragma unroll
        for (int nt = 0; nt < 4; ++nt)
            bOf[nt] = wn * 64 + nt * 16 + fr;                    // col idx
    }

    STAGE(As0, Bb0, kb);
    __syncthreads();
    int cur = 0;
    for (int i = 0; i < nit; ++i) {
        const float* Ac = cur ? As1 : As0;
        const float* Bc = cur ? Bb1 : Bb0;
        if (i + 1 < nit) STAGE(cur ? As0 : As1, cur ? Bb0 : Bb1, kb + (i + 1) * 32);

        f4 x0 = *(const f4*)(Ac + aO00 * 4);
        f4 x1 = *(const f4*)(Ac + aO01 * 4);
        f4 x2 = *(const f4*)(Ac + aO10 * 4);
        f4 x3 = *(const f4*)(Ac + aO11 * 4);
        bf8_t af0, af1;
#pragma unroll
        for (int q = 0; q < 4; ++q) {
            af0[q] = (__bf16)x0[q]; af0[4 + q] = (__bf16)x1[q];
            af1[q] = (__bf16)x2[q]; af1[4 + q] = (__bf16)x3[q];
        }
#pragma unroll
        for (int nt = 0; nt < 4; ++nt) {
            bf8_t bv;
            if constexpr (BMODE == 0) {
                bv = *(const bf8_t*)((const __bf16*)Bc + bOf[nt]);
            } else {
                const float* bb = Bc + fq * 128 + bOf[nt];
#pragma unroll
                for (int d2 = 0; d2 < 8; ++d2) bv[d2] = (__bf16)bb[d2 * 128];
            }
            acc[0][nt] = __builtin_amdgcn_mfma_f32_16x16x32_bf16(af0, bv, acc[0][nt], 0, 0, 0);
            acc[1][nt] = __builtin_amdgcn_mfma_f32_16x16x32_bf16(af1, bv, acc[1][nt], 0, 0, 0);
        }
        __syncthreads();
        cur ^= 1;
    }

    float* Cp; long ldcp;
    const bool fin = (ksplit == 1);
    if (!fin) { Cp = C + (long)(batch * ksplit + kz) * M * N; ldcp = N; }
    else      { Cp = C + (long)batch * sC;                    ldcp = ldc; }

    const int rb = m0 + wm * 32 + (lane >> 4) * 4;
    const int cb_ = n0 + wn * 64 + fr;
    float rowpart[2][4] = {{0.f,0.f,0.f,0.f},{0.f,0.f,0.f,0.f}};
#pragma unroll
    for (int mt = 0; mt < 2; ++mt) {
#pragma unroll
        for (int nt = 0; nt < 4; ++nt) {
            const int c = cb_ + nt * 16;
            const float bvl = (fin && bias) ? bias[c] : 0.f;
#pragma unroll
            for (int v = 0; v < 4; ++v) {
                const int r = rb + mt * 16 + v;
                if (r < M) {
                    float val = acc[mt][nt][v] + bvl;
                    if (fin && relu) val = fmaxf(val, 0.f);
                    if (fin && addsrc) val += addsrc[(long)r * ldcp + c];
                    Cp[(long)r * ldcp + c] = val;
                    rowpart[mt][v] += val;
                }
            }
        }
    }
    if (rsum) {
#pragma unroll
        for (int mt = 0; mt < 2; ++mt) {
#pragma unroll
            for (int v = 0; v < 4; ++v) {
                float s = rowpart[mt][v];
                s += __shfl_xor(s, 1); s += __shfl_xor(s, 2);
                s += __shfl_xor(s, 4); s += __shfl_xor(s, 8);
                const int r = rb + mt * 16 + v;
                if (fr == 0 && r < M) atomicAdd(&rsum[(long)bz * M + r], s);
            }
        }
    }
}

// ---------------------------------------------------------------------------
// GEMM1 register-direct path: barrier-free, LDS-free, fully-unrolled K-loop.
// Both MFMA fragments are contiguous 16B loads straight from memory:
//   A-frag: 8 consecutive fp32 of an x row; B-frag: 8 consecutive bf16 of a
//   WembT row. No staging -> no vmcnt(0) drain; scheduler hoists loads.
// Tile 64x128, kchunk=800 (25 steps), partials to part[kz*2048*128 + ...].
// ---------------------------------------------------------------------------
__device__ __forceinline__ void gemm1_reg(const float* __restrict__ x,
                                          const __bf16* __restrict__ WembT,
                                          float* __restrict__ part,
                                          int bm, int kz) {
    const int t = threadIdx.x;
    const int lane = t & 63, w = t >> 6;
    const int wm = w >> 1, wn = w & 1;
    const int fr = lane & 15;
    const int fq = (lane >> 4) * 8;
    const int m0 = bm * 64;
    const int kb = kz * 800;

    const float* aB0 = x + (long)(m0 + wm * 32 + fr) * 32000 + kb + fq;
    const float* aB1 = aB0 + 16L * 32000;
    const __bf16* bB0 = WembT + (long)(wn * 64 +  0 + fr) * 32000 + kb + fq;
    const __bf16* bB1 = WembT + (long)(wn * 64 + 16 + fr) * 32000 + kb + fq;
    const __bf16* bB2 = WembT + (long)(wn * 64 + 32 + fr) * 32000 + kb + fq;
    const __bf16* bB3 = WembT + (long)(wn * 64 + 48 + fr) * 32000 + kb + fq;

    f4 acc[2][4];
#pragma unroll
    for (int mt = 0; mt < 2; ++mt)
#pragma unroll
        for (int nt = 0; nt < 4; ++nt) acc[mt][nt] = (f4){0.f, 0.f, 0.f, 0.f};

#pragma unroll
    for (int i = 0; i < 25; ++i) {
        const int k = i * 32;
        f4 a0 = *(const f4*)(aB0 + k);
        f4 a1 = *(const f4*)(aB0 + k + 4);
        f4 a2 = *(const f4*)(aB1 + k);
        f4 a3 = *(const f4*)(aB1 + k + 4);
        bf8_t b0 = *(const bf8_t*)(bB0 + k);
        bf8_t b1 = *(const bf8_t*)(bB1 + k);
        bf8_t b2 = *(const bf8_t*)(bB2 + k);
        bf8_t b3 = *(const bf8_t*)(bB3 + k);
        bf8_t af0, af1;
#pragma unroll
        for (int q = 0; q < 4; ++q) {
            af0[q] = (__bf16)a0[q]; af0[4 + q] = (__bf16)a1[q];
            af1[q] = (__bf16)a2[q]; af1[4 + q] = (__bf16)a3[q];
        }
        acc[0][0] = __builtin_amdgcn_mfma_f32_16x16x32_bf16(af0, b0, acc[0][0], 0, 0, 0);
        acc[1][0] = __builtin_amdgcn_mfma_f32_16x16x32_bf16(af1, b0, acc[1][0], 0, 0, 0);
        acc[0][1] = __builtin_amdgcn_mfma_f32_16x16x32_bf16(af0, b1, acc[0][1], 0, 0, 0);
        acc[1][1] = __builtin_amdgcn_mfma_f32_16x16x32_bf16(af1, b1, acc[1][1], 0, 0, 0);
        acc[0][2] = __builtin_amdgcn_mfma_f32_16x16x32_bf16(af0, b2, acc[0][2], 0, 0, 0);
        acc[1][2] = __builtin_amdgcn_mfma_f32_16x16x32_bf16(af1, b2, acc[1][2], 0, 0, 0);
        acc[0][3] = __builtin_amdgcn_mfma_f32_16x16x32_bf16(af0, b3, acc[0][3], 0, 0, 0);
        acc[1][3] = __builtin_amdgcn_mfma_f32_16x16x32_bf16(af1, b3, acc[1][3], 0, 0, 0);
    }

    float* Cp = part + (long)kz * 262144;
    const int rb = m0 + wm * 32 + (lane >> 4) * 4;
    const int cb_ = wn * 64 + fr;
#pragma unroll
    for (int mt = 0; mt < 2; ++mt)
#pragma unroll
        for (int nt = 0; nt < 4; ++nt)
#pragma unroll
            for (int v = 0; v < 4; ++v)
                Cp[(long)(rb + mt * 16 + v) * 128 + cb_ + nt * 16] = acc[mt][nt][v];
}

// Generic launch wrapper (R6 DEPTH=2)
template<int BMODE>
__global__ __launch_bounds__(256)
void gemm_v2(const float* A, const void* Bv, const void* B2v, float* C,
             const float* bias, const float* addsrc, float* rsum,
             int M, int N, int K, int lda, int ldb, int ldc, int kswitch,
             long sA, long sB, long sC, int ksplit, int kchunk, int relu) {
    __shared__ __align__(16) float AsF[2][2048];
    __shared__ __align__(16) float Bbuf[2][BMODE ? 4096 : 2048];
    gemm_dev<BMODE>(&AsF[0][0], &AsF[1][0], &Bbuf[0][0], &Bbuf[1][0],
                    A, Bv, B2v, C, bias, addsrc, rsum,
                    M, N, K, lda, ldb, ldc, kswitch, sA, sB, sC,
                    ksplit, kchunk, relu,
                    blockIdx.x, blockIdx.y, blockIdx.z);
}

// mega1: GEMM1 (1280 blocks, reg-direct, XCD-grouped: 40 kz x 32 bm)
//        + Q1 (2) + Q2 (4) + Q3 (10) via LDS path.
__global__ __launch_bounds__(256)
void mega1_kernel(const float* __restrict__ x, const __bf16* __restrict__ WembT,
                  float* __restrict__ partG1,
                  const float* __restrict__ P1, const __bf16* __restrict__ Q1T,
                  float* __restrict__ Q1o, const float* __restrict__ bq1,
                  const float* __restrict__ P2, const __bf16* __restrict__ Q2T,
                  float* __restrict__ Q2o, const float* __restrict__ bq2,
                  const float* __restrict__ P3, const __bf16* __restrict__ Q3T,
                  float* __restrict__ Q3o, const float* __restrict__ bq3) {
    __shared__ __align__(16) float AsF[2][2048];
    __shared__ __align__(16) float Bbuf[2][2048];
    float* A0 = &AsF[0][0]; float* A1 = &AsF[1][0];
    float* B0 = &Bbuf[0][0]; float* B1 = &Bbuf[1][0];
    const int bid = blockIdx.x;
    if (bid < 1280) {
        const int xc = bid & 7, j = bid >> 3;
        const int kz = xc + ((j >> 5) << 3);   // 40 kz slices, 5 per XCD
        const int bm = j & 31;
        gemm1_reg(x, WembT, partG1, bm, kz);
    } else if (bid < 1282) {
        gemm_dev<0>(A0, A1, B0, B1, P1, Q1T, nullptr, Q1o,
                    bq1, nullptr, nullptr,
                    128, 128, 256, 256, 256, 128, 256,
                    0, 0, 0, 1, 256, 1, 0, bid - 1280, 0);
    } else if (bid < 1286) {
        const int l = bid - 1282;
        gemm_dev<0>(A0, A1, B0, B1, P2, Q2T, nullptr, Q2o,
                    bq2, nullptr, nullptr,
                    128, 256, 512, 512, 512, 256, 512,
                    0, 0, 0, 1, 512, 1, l & 1, l >> 1, 0);
    } else {
        const int l = bid - 1286;
        gemm_dev<0>(A0, A1, B0, B1, P3, Q3T, nullptr, Q3o,
                    bq3, nullptr, nullptr,
                    128, 640, 1280, 1280, 1280, 640, 1280,
                    0, 0, 0, 1, 1280, 1, l % 5, l / 5, 0);
    }
}

// out[idx] = [relu](sum_z part[z*MN+idx] + bias[idx%N])
__global__ __launch_bounds__(256)
void reduce_splitk(const float* __restrict__ part, float* __restrict__ outp,
                   const float* __restrict__ bias, int MN, int N, int ksplit,
                   int relu) {
    int idx = blockIdx.x * 256 + threadIdx.x;
    if (idx >= MN) return;
    float s = 0.f;
    for (int z = 0; z < ksplit; ++z) s += part[(long)z * MN + idx];
    if (bias) s += bias[idx % N];
    if (relu) s = fmaxf(s, 0.f);
    outp[idx] = s;
}

// GEMM1 reduce: h1 = relu(sum_z part + b_emb) + Q1; rs1 = rowsum(h1).
__global__ __launch_bounds__(256)
void reduce_rs_kernel(const float* __restrict__ part, float* __restrict__ h1,
                      const float* __restrict__ bias, const float* __restrict__ Q1,
                      float* __restrict__ rs1, int ksplit) {
    const int t = threadIdx.x;
    const int idx = blockIdx.x * 256 + t;
    float s = 0.f;
    for (int z = 0; z < ksplit; ++z) s += part[(long)z * 262144 + idx];
    s += bias[idx & 127];
    s = fmaxf(s, 0.f);
    s += Q1[idx & 16383];
    h1[idx] = s;
    float r = s;
    for (int off = 32; off > 0; off >>= 1) r += __shfl_down(r, off, 64);
    __shared__ float p[4];
    const int w = t >> 6, lane = t & 63;
    if (lane == 0) p[w] = r;
    __syncthreads();
    if (t < 2) rs1[(blockIdx.x << 1) + t] = p[t * 2] + p[t * 2 + 1];
}

// ---------------------------------------------------------------------------
extern "C" void kernel_launch(void* const* d_in, const int* in_sizes, int n_in,
                              void* d_out, int out_size, void* d_ws, size_t ws_size,
                              hipStream_t stream) {
    const float* x       = (const float*)d_in[0];
    const float* W_emb   = (const float*)d_in[1];
    const float* b_emb   = (const float*)d_in[2];
    const float* W_pos1  = (const float*)d_in[3];
    const float* b_pos1  = (const float*)d_in[4];
    const float* W_red   = (const float*)d_in[5];
    const float* b_red   = (const float*)d_in[6];
    const float* W_pos2  = (const float*)d_in[7];
    const float* b_pos2  = (const float*)d_in[8];
    const float* W_red2  = (const float*)d_in[9];
    const float* b_red2  = (const float*)d_in[10];
    const float* W_pos3  = (const float*)d_in[11];
    const float* b_pos3  = (const float*)d_in[12];
    const float* W_down2 = (const float*)d_in[13];
    const float* b_down2 = (const float*)d_in[14];
    const float* W_flat  = (const float*)d_in[15];
    const float* b_flat  = (const float*)d_in[16];
    const float* W_d1    = (const float*)d_in[17];
    const float* b_d1    = (const float*)d_in[18];
    const float* W_d2    = (const float*)d_in[19];
    const float* b_d2    = (const float*)d_in[20];
    const float* W_d3    = (const float*)d_in[21];
    const float* b_d3    = (const float*)d_in[22];
    const float* W_p1    = (const float*)d_in[23];
    const float* b_p1    = (const float*)d_in[24];
    const float* W_p2    = (const float*)d_in[25];
    const float* b_p2    = (const float*)d_in[26];
    float* out = (float*)d_out;
    float* ws  = (float*)d_ws;

    size_t o = 0;
    auto alloc = [&](size_t n) { size_t p = o; o += (n + 63) & ~(size_t)63; return p; };
    const size_t oP1 = alloc(128 * 256);
    const size_t oP2 = alloc(128 * 512);
    const size_t oP3 = alloc(128 * 1280);
    const size_t oQ1 = alloc(128 * 128);
    const size_t oQ2 = alloc(128 * 256);
    const size_t oQ3 = alloc(128 * 640);
    const size_t oBC = alloc(32000);
    const size_t oH1 = alloc(2048 * 128);
    const size_t oRS1 = alloc(2048);
    const size_t oRS2 = alloc(2048);
    const size_t oH2 = alloc(2048 * 256);
    const size_t oH3 = alloc(2048 * 640);
    const size_t oH4 = alloc(2048 * 512);
    const size_t oH5 = alloc(16 * 512);
    const size_t oH6c = alloc(16 * 1024);    // h6 at stride 1024 (cols 0..511)
    const size_t oCat = alloc(16 * 1024);    // [h68 | h7] concat, stride 1024
    const size_t oM1 = alloc(16 * 32768);
    const size_t oM2 = alloc(16 * 163840);
    const size_t oWembT = alloc(2048000);    // bf16 buffers sized in floats
    const size_t oWd2T  = alloc(163840);
    const size_t oQ1T   = alloc(16384);
    const size_t oQ2T   = alloc(65536);
    const size_t oQ3T   = alloc(409600);
    const size_t oRegA = alloc(40u * 262144); // partials: GEMM1(40) / W_flat(64x8192)
    const size_t oPartG1 = oRegA, oPartF = oRegA;
    (void)ws_size; (void)in_sizes; (void)n_in; (void)out_size;

    __bf16* WembT = (__bf16*)(ws + oWembT);
    __bf16* Wd2T  = (__bf16*)(ws + oWd2T);
    __bf16* Q1T   = (__bf16*)(ws + oQ1T);
    __bf16* Q2T   = (__bf16*)(ws + oQ2T);
    __bf16* Q3T   = (__bf16*)(ws + oQ3T);

    dim3 blk(256);

    // 1. prep: transposes + pos encodings + combined bias + rs2 zero
    prep_kernel<<<dim3(6437), blk, 0, stream>>>(
        ws + oP1, ws + oP2, ws + oP3, b_p1, b_p2, ws + oBC, ws + oRS2,
        W_emb, WembT, W_down2, Wd2T, W_pos1, Q1T, W_pos2, Q2T, W_pos3, Q3T);
    // 2. mega1: GEMM1 partials (reg-direct, ksplit=40) + Q1 + Q2 + Q3
    mega1_kernel<<<dim3(1296), blk, 0, stream>>>(
        x, WembT, ws + oPartG1,
        ws + oP1, Q1T, ws + oQ1, b_pos1,
        ws + oP2, Q2T, ws + oQ2, b_pos2,
        ws + oP3, Q3T, ws + oQ3, b_pos3);
    // 3. h1 = relu(sum + b_emb) + Q1 ; rs1 = rowsum(h1)
    reduce_rs_kernel<<<dim3(1024), blk, 0, stream>>>(ws + oPartG1, ws + oH1,
                                                     b_emb, ws + oQ1, ws + oRS1, 40);
    // 4. M1 = rs1(16x128) @ W_red viewed (128 x 32768)
    gemm_v2<1><<<dim3(256, 1, 1), blk, 0, stream>>>(ws + oRS1, W_red, nullptr,
        ws + oM1, nullptr, nullptr, nullptr,
        16, 32768, 128, 128, 32768, 32768, 1 << 30, 0, 0, 0, 1, 128, 0);
    // 5. h2 = relu(h1[b] @ M1[b] + b_red) + Q2 ; rs2 += rowsums (atomic)
    gemm_v2<1><<<dim3(2, 2, 16), blk, 0, stream>>>(ws + oH1, ws + oM1, nullptr,
        ws + oH2, b_red, ws + oQ2, ws + oRS2,
        128, 256, 128, 128, 256, 256, 1 << 30, 16384, 32768, 32768, 1, 128, 1);
    // 6. M2 = rs2(16x128) @ W_red2 viewed (128 x 163840)
    gemm_v2<1><<<dim3(1280, 1, 1), blk, 0, stream>>>(ws + oRS2, W_red2, nullptr,
        ws + oM2, nullptr, nullptr, nullptr,
        16, 163840, 128, 128, 163840, 163840, 1 << 30, 0, 0, 0, 1, 128, 0);
    // 7. h3 = relu(h2[b] @ M2[b] + b_red2) + Q3
    gemm_v2<1><<<dim3(5, 2, 16), blk, 0, stream>>>(ws + oH2, ws + oM2, nullptr,
        ws + oH3, b_red2, ws + oQ3, nullptr,
        128, 640, 256, 256, 640, 640, 1 << 30, 32768, 163840, 81920, 1, 256, 1);
    // 8. h4 = relu(h3 @ W_down2 + b_down2)
    gemm_v2<0><<<dim3(4, 32, 1), blk, 0, stream>>>(ws + oH3, Wd2T, nullptr,
        ws + oH4, b_down2, nullptr, nullptr,
        2048, 512, 640, 640, 640, 512, 1 << 30, 0, 0, 0, 1, 640, 1);
    // 9. h5 partials = h4 viewed (16x65536) @ W_flat, split-K 64
    gemm_v2<1><<<dim3(4, 1, 64), blk, 0, stream>>>(ws + oH4, W_flat, nullptr,
        ws + oPartF, nullptr, nullptr, nullptr,
        16, 512, 65536, 65536, 512, 512, 1 << 30, 0, 0, 0, 64, 1024, 0);
    // 10. h5 = relu(sum + b_flat)
    reduce_splitk<<<dim3(32), blk, 0, stream>>>(ws + oPartF, ws + oH5, b_flat,
                                                8192, 512, 64, 1);
    // 11-13. dense chain into stride-1024 concat layout
    gemm_v2<1><<<dim3(4, 1, 1), blk, 0, stream>>>(ws + oH5, W_d1, nullptr,
        ws + oH6c, b_d1, nullptr, nullptr,
        16, 512, 512, 512, 512, 1024, 1 << 30, 0, 0, 0, 1, 512, 1);
    gemm_v2<1><<<dim3(4, 1, 1), blk, 0, stream>>>(ws + oH6c, W_d2, nullptr,
        ws + oCat + 512, b_d2, nullptr, nullptr,
        16, 512, 512, 1024, 512, 1024, 1 << 30, 0, 0, 0, 1, 512, 1);
    gemm_v2<1><<<dim3(4, 1, 1), blk, 0, stream>>>(ws + oCat + 512, W_d3, nullptr,
        ws + oCat, b_d3, ws + oH6c, nullptr,
        16, 512, 512, 1024, 512, 1024, 1 << 30, 0, 0, 0, 1, 512, 1);
    // 14. out = [h68|h7](16x1024) @ [W_p1;W_p2](1024x32000) + (2*b_p1+b_p2)
    gemm_v2<1><<<dim3(250, 1, 1), blk, 0, stream>>>(ws + oCat, W_p1, W_p2,
        out, ws + oBC, nullptr, nullptr,
        16, 32000, 1024, 1024, 32000, 32000, 512, 0, 0, 0, 1, 1024, 0);
}

// Round 12
// 400.050 us; speedup vs baseline: 1.0634x; 1.0634x over previous
//
#include <hip/hip_runtime.h>

typedef float  f4   __attribute__((ext_vector_type(4)));
typedef __bf16 bf8_t __attribute__((ext_vector_type(8)));
typedef __bf16 bf4_t __attribute__((ext_vector_type(4)));

__device__ __forceinline__ void glds16(const void* g, void* l) {
    __builtin_amdgcn_global_load_lds(
        (const __attribute__((address_space(1))) void*)g,
        (__attribute__((address_space(3))) void*)l, 16, 0, 0);
}

// ---------------------------------------------------------------------------
// prep: weight transposes (blocks 0..5279) + pos encodings / combined bias /
// rs2 zero (blocks 5280..6436).
// ---------------------------------------------------------------------------
__global__ __launch_bounds__(256)
void prep_kernel(float* __restrict__ P1, float* __restrict__ P2,
                 float* __restrict__ P3,
                 const float* __restrict__ bp1, const float* __restrict__ bp2,
                 float* __restrict__ bc, float* __restrict__ rs2,
                 const float* __restrict__ Wemb, __bf16* __restrict__ WembT,
                 const float* __restrict__ Wd2, __bf16* __restrict__ Wd2T,
                 const float* __restrict__ Wq1, __bf16* __restrict__ Wq1T,
                 const float* __restrict__ Wq2, __bf16* __restrict__ Wq2T,
                 const float* __restrict__ Wq3, __bf16* __restrict__ Wq3T) {
    const int bid = blockIdx.x;
    const int t = threadIdx.x;
    if (bid < 5280) {
        const float* src; __bf16* dst; int CN, RK, tn, local;
        if (bid < 4000)      { src = Wemb; dst = WembT; RK = 32000; CN = 128; tn = 4;  local = bid; }
        else if (bid < 4320) { src = Wd2;  dst = Wd2T;  RK = 640;   CN = 512; tn = 16; local = bid - 4000; }
        else if (bid < 4352) { src = Wq1;  dst = Wq1T;  RK = 256;   CN = 128; tn = 4;  local = bid - 4320; }
        else if (bid < 4480) { src = Wq2;  dst = Wq2T;  RK = 512;   CN = 256; tn = 8;  local = bid - 4352; }
        else                 { src = Wq3;  dst = Wq3T;  RK = 1280;  CN = 640; tn = 20; local = bid - 4480; }
        const int kt = local / tn, ntl = local - kt * tn;
        const int k0 = kt * 32, n0 = ntl * 32;
        __shared__ float tile[32][33];
        const int r = t >> 3, c4 = (t & 7) * 4;
        const f4 v = *(const f4*)(src + (long)(k0 + r) * CN + n0 + c4);
        tile[r][c4] = v[0]; tile[r][c4 + 1] = v[1];
        tile[r][c4 + 2] = v[2]; tile[r][c4 + 3] = v[3];
        __syncthreads();
        bf4_t o2;
        o2[0] = (__bf16)tile[c4][r];     o2[1] = (__bf16)tile[c4 + 1][r];
        o2[2] = (__bf16)tile[c4 + 2][r]; o2[3] = (__bf16)tile[c4 + 3][r];
        *(bf4_t*)(dst + (long)(n0 + r) * RK + k0 + c4) = o2;
        return;
    }
    int idx = (bid - 5280) * 256 + t;
    const int n1 = 128 * 256, n2 = 128 * 512;      // P3: 128*1280
    const int nP = 262144;
    if (idx < nP) {
        float* P; int d, local;
        if (idx < n1)           { P = P1; d = 256;  local = idx; }
        else if (idx < n1 + n2) { P = P2; d = 512;  local = idx - n1; }
        else                    { P = P3; d = 1280; local = idx - n1 - n2; }
        int s = local / d;
        int k = local - s * d;
        int i = k >> 1;
        float ang = (float)s * powf(10000.0f, (-2.0f * (float)i) / (float)d);
        P[local] = (k & 1) ? cosf(ang) : sinf(ang);
    } else if (idx < nP + 32000) {
        int j = idx - nP;
        bc[j] = 2.f * bp1[j] + bp2[j];
    } else if (idx < nP + 32000 + 2048) {
        rs2[idx - nP - 32000] = 0.f;
    }
}

// ---------------------------------------------------------------------------
// Core MFMA GEMM device body — exact R6 proven loop:
//   STAGE(next buf) | COMPUTE(cur) | __syncthreads.
//   BMODE 0: B = bf16 [N][K] pre-transposed; BMODE 1: B = fp32 [K][N] natural
//            (optional B2 switch at k >= kswitch, same ldb).
//   rsum != nullptr (ksplit==1): atomic row-sum accumulation (pre-zeroed).
// ---------------------------------------------------------------------------
template<int BMODE>
__device__ __forceinline__ void gemm_dev(
    float* As0, float* As1, float* Bb0, float* Bb1,
    const float* __restrict__ A, const void* __restrict__ Bv,
    const void* __restrict__ B2v, float* __restrict__ C,
    const float* __restrict__ bias, const float* __restrict__ addsrc,
    float* __restrict__ rsum,
    int M, int N, int K, int lda, int ldb, int ldc, int kswitch,
    long sA, long sB, long sC, int ksplit, int kchunk, int relu,
    int bn, int bm, int bz) {

    const int t = threadIdx.x;
    const int batch = bz / ksplit;
    const int kz = bz - batch * ksplit;
    const int m0 = bm * 64, n0 = bn * 128;
    const int kb = kz * kchunk;
    const int ke = (kb + kchunk < K) ? (kb + kchunk) : K;
    const int nit = (ke - kb + 31) >> 5;

    const int lane = t & 63;
    const int w = t >> 6;
    const int wm = w >> 1, wn = w & 1;
    const int fr = lane & 15;
    const int fq = (lane >> 4) * 8;

    f4 acc[2][4];
#pragma unroll
    for (int mt = 0; mt < 2; ++mt)
#pragma unroll
        for (int nt = 0; nt < 4; ++nt) acc[mt][nt] = (f4){0.f, 0.f, 0.f, 0.f};

    const float* Ab = A + (long)batch * sA;
    const int mvalid = M - m0;

    const int ra = t >> 3;
    const int ja = (t & 7) ^ (ra & 7);
    const float* aS0 = Ab + (long)(m0 + ra) * lda + 4 * ja;
    const float* aS1 = aS0 + 32L * lda;

    const __bf16* bTS0 = nullptr; const __bf16* bTS1 = nullptr;
    const float* bNS0 = nullptr; const float* bNS2 = nullptr;
    if constexpr (BMODE == 0) {
        const __bf16* BT = (const __bf16*)Bv + (long)batch * sB;
        const int nb = t >> 2;
        const int fb = (nb & 3) ^ ((nb >> 2) & 3);
        const int jb = (t & 3) ^ fb;
        bTS0 = BT + (long)(n0 + nb) * ldb + 8 * jb;
        bTS1 = bTS0 + 64L * ldb;
    } else {
        const float* Bn = (const float*)Bv + (long)batch * sB;
        bNS0 = Bn + (long)(t >> 5) * ldb + n0 + (t & 31) * 4;
        const float* Bn2 = (const float*)(B2v ? B2v : Bv);
        bNS2 = Bn2 + (long)(t >> 5) * ldb + n0 + (t & 31) * 4;
    }

    auto STAGE = [&](float* Ad, float* Bd, int k0) {
        if (ra < mvalid)      glds16(aS0 + k0, Ad + 4 * t);
        if (ra + 32 < mvalid) glds16(aS1 + k0, Ad + 1024 + 4 * t);
        if constexpr (BMODE == 0) {
            glds16(bTS0 + k0, Bd + 4 * t);
            glds16(bTS1 + k0, Bd + 1024 + 4 * t);
        } else {
            const float* bp = (k0 < kswitch) ? (bNS0 + (long)k0 * ldb)
                                             : (bNS2 + (long)(k0 - kswitch) * ldb);
            glds16(bp,             Bd + 4 * t);
            glds16(bp + 8L * ldb,  Bd + 1024 + 4 * t);
            glds16(bp + 16L * ldb, Bd + 2048 + 4 * t);
            glds16(bp + 24L * ldb, Bd + 3072 + 4 * t);
        }
    };

    // frag-read offsets (constant across K)
    const int R0 = wm * 32 + fr, R1 = R0 + 16;
    const int jq = (lane >> 4) * 2;
    const int x7 = R0 & 7;
    const int aO00 = R0 * 8 + (jq ^ x7);
    const int aO01 = R0 * 8 + ((jq + 1) ^ x7);
    const int aO10 = R1 * 8 + (jq ^ x7);
    const int aO11 = R1 * 8 + ((jq + 1) ^ x7);
    int bOf[4];
    if constexpr (BMODE == 0) {
        const int fbc = (fr & 3) ^ ((fr >> 2) & 3);
        const int jb2 = (lane >> 4) ^ fbc;
#pragma unroll
        for (int nt = 0; nt < 4; ++nt)
            bOf[nt] = ((wn * 64 + nt * 16 + fr) * 4 + jb2) * 8;  // bf16 idx
    } else {
#pragma unroll
        for (int nt = 0; nt < 4; ++nt)
            bOf[nt] = wn * 64 + nt * 16 + fr;                    // col idx
    }

    STAGE(As0, Bb0, kb);
    __syncthreads();
    int cur = 0;
    for (int i = 0; i < nit; ++i) {
        const float* Ac = cur ? As1 : As0;
        const float* Bc = cur ? Bb1 : Bb0;
        if (i + 1 < nit) STAGE(cur ? As0 : As1, cur ? Bb0 : Bb1, kb + (i + 1) * 32);

        f4 x0 = *(const f4*)(Ac + aO00 * 4);
        f4 x1 = *(const f4*)(Ac + aO01 * 4);
        f4 x2 = *(const f4*)(Ac + aO10 * 4);
        f4 x3 = *(const f4*)(Ac + aO11 * 4);
        bf8_t af0, af1;
#pragma unroll
        for (int q = 0; q < 4; ++q) {
            af0[q] = (__bf16)x0[q]; af0[4 + q] = (__bf16)x1[q];
            af1[q] = (__bf16)x2[q]; af1[4 + q] = (__bf16)x3[q];
        }
#pragma unroll
        for (int nt = 0; nt < 4; ++nt) {
            bf8_t bv;
            if constexpr (BMODE == 0) {
                bv = *(const bf8_t*)((const __bf16*)Bc + bOf[nt]);
            } else {
                const float* bb = Bc + fq * 128 + bOf[nt];
#pragma unroll
                for (int d2 = 0; d2 < 8; ++d2) bv[d2] = (__bf16)bb[d2 * 128];
            }
            acc[0][nt] = __builtin_amdgcn_mfma_f32_16x16x32_bf16(af0, bv, acc[0][nt], 0, 0, 0);
            acc[1][nt] = __builtin_amdgcn_mfma_f32_16x16x32_bf16(af1, bv, acc[1][nt], 0, 0, 0);
        }
        __syncthreads();
        cur ^= 1;
    }

    float* Cp; long ldcp;
    const bool fin = (ksplit == 1);
    if (!fin) { Cp = C + (long)(batch * ksplit + kz) * M * N; ldcp = N; }
    else      { Cp = C + (long)batch * sC;                    ldcp = ldc; }

    const int rb = m0 + wm * 32 + (lane >> 4) * 4;
    const int cb_ = n0 + wn * 64 + fr;
    float rowpart[2][4] = {{0.f,0.f,0.f,0.f},{0.f,0.f,0.f,0.f}};
#pragma unroll
    for (int mt = 0; mt < 2; ++mt) {
#pragma unroll
        for (int nt = 0; nt < 4; ++nt) {
            const int c = cb_ + nt * 16;
            const float bvl = (fin && bias) ? bias[c] : 0.f;
#pragma unroll
            for (int v = 0; v < 4; ++v) {
                const int r = rb + mt * 16 + v;
                if (r < M) {
                    float val = acc[mt][nt][v] + bvl;
                    if (fin && relu) val = fmaxf(val, 0.f);
                    if (fin && addsrc) val += addsrc[(long)r * ldcp + c];
                    Cp[(long)r * ldcp + c] = val;
                    rowpart[mt][v] += val;
                }
            }
        }
    }
    if (rsum) {
#pragma unroll
        for (int mt = 0; mt < 2; ++mt) {
#pragma unroll
            for (int v = 0; v < 4; ++v) {
                float s = rowpart[mt][v];
                s += __shfl_xor(s, 1); s += __shfl_xor(s, 2);
                s += __shfl_xor(s, 4); s += __shfl_xor(s, 8);
                const int r = rb + mt * 16 + v;
                if (fr == 0 && r < M) atomicAdd(&rsum[(long)bz * M + r], s);
            }
        }
    }
}

// Generic launch wrapper (R6 DEPTH=2)
template<int BMODE>
__global__ __launch_bounds__(256)
void gemm_v2(const float* A, const void* Bv, const void* B2v, float* C,
             const float* bias, const float* addsrc, float* rsum,
             int M, int N, int K, int lda, int ldb, int ldc, int kswitch,
             long sA, long sB, long sC, int ksplit, int kchunk, int relu) {
    __shared__ __align__(16) float AsF[2][2048];
    __shared__ __align__(16) float Bbuf[2][BMODE ? 4096 : 2048];
    gemm_dev<BMODE>(&AsF[0][0], &AsF[1][0], &Bbuf[0][0], &Bbuf[1][0],
                    A, Bv, B2v, C, bias, addsrc, rsum,
                    M, N, K, lda, ldb, ldc, kswitch, sA, sB, sC,
                    ksplit, kchunk, relu,
                    blockIdx.x, blockIdx.y, blockIdx.z);
}

// mega1: GEMM1 (1280 blocks, LDS path, XCD-grouped: 40 kz x 32 bm, 5/CU)
//        + Q1 (2) + Q2 (4) + Q3 (10).
__global__ __launch_bounds__(256)
void mega1_kernel(const float* __restrict__ x, const __bf16* __restrict__ WembT,
                  float* __restrict__ partG1,
                  const float* __restrict__ P1, const __bf16* __restrict__ Q1T,
                  float* __restrict__ Q1o, const float* __restrict__ bq1,
                  const float* __restrict__ P2, const __bf16* __restrict__ Q2T,
                  float* __restrict__ Q2o, const float* __restrict__ bq2,
                  const float* __restrict__ P3, const __bf16* __restrict__ Q3T,
                  float* __restrict__ Q3o, const float* __restrict__ bq3) {
    __shared__ __align__(16) float AsF[2][2048];
    __shared__ __align__(16) float Bbuf[2][2048];
    float* A0 = &AsF[0][0]; float* A1 = &AsF[1][0];
    float* B0 = &Bbuf[0][0]; float* B1 = &Bbuf[1][0];
    const int bid = blockIdx.x;
    if (bid < 1280) {
        const int xc = bid & 7, j = bid >> 3;
        const int bz = xc + ((j >> 5) << 3);   // 40 kz slices, 5 per XCD
        const int bm = j & 31;
        gemm_dev<0>(A0, A1, B0, B1, x, WembT, nullptr, partG1,
                    nullptr, nullptr, nullptr,
                    2048, 128, 32000, 32000, 32000, 128, 32000,
                    0, 0, 0, 40, 800, 0, 0, bm, bz);
    } else if (bid < 1282) {
        gemm_dev<0>(A0, A1, B0, B1, P1, Q1T, nullptr, Q1o,
                    bq1, nullptr, nullptr,
                    128, 128, 256, 256, 256, 128, 256,
                    0, 0, 0, 1, 256, 1, 0, bid - 1280, 0);
    } else if (bid < 1286) {
        const int l = bid - 1282;
        gemm_dev<0>(A0, A1, B0, B1, P2, Q2T, nullptr, Q2o,
                    bq2, nullptr, nullptr,
                    128, 256, 512, 512, 512, 256, 512,
                    0, 0, 0, 1, 512, 1, l & 1, l >> 1, 0);
    } else {
        const int l = bid - 1286;
        gemm_dev<0>(A0, A1, B0, B1, P3, Q3T, nullptr, Q3o,
                    bq3, nullptr, nullptr,
                    128, 640, 1280, 1280, 1280, 640, 1280,
                    0, 0, 0, 1, 1280, 1, l % 5, l / 5, 0);
    }
}

// out[idx] = [relu](sum_z part[z*MN+idx] + bias[idx%N])
__global__ __launch_bounds__(256)
void reduce_splitk(const float* __restrict__ part, float* __restrict__ outp,
                   const float* __restrict__ bias, int MN, int N, int ksplit,
                   int relu) {
    int idx = blockIdx.x * 256 + threadIdx.x;
    if (idx >= MN) return;
    float s = 0.f;
    for (int z = 0; z < ksplit; ++z) s += part[(long)z * MN + idx];
    if (bias) s += bias[idx % N];
    if (relu) s = fmaxf(s, 0.f);
    outp[idx] = s;
}

// GEMM1 reduce: h1 = relu(sum_z part + b_emb) + Q1; rs1 = rowsum(h1).
__global__ __launch_bounds__(256)
void reduce_rs_kernel(const float* __restrict__ part, float* __restrict__ h1,
                      const float* __restrict__ bias, const float* __restrict__ Q1,
                      float* __restrict__ rs1, int ksplit) {
    const int t = threadIdx.x;
    const int idx = blockIdx.x * 256 + t;
    float s = 0.f;
    for (int z = 0; z < ksplit; ++z) s += part[(long)z * 262144 + idx];
    s += bias[idx & 127];
    s = fmaxf(s, 0.f);
    s += Q1[idx & 16383];
    h1[idx] = s;
    float r = s;
    for (int off = 32; off > 0; off >>= 1) r += __shfl_down(r, off, 64);
    __shared__ float p[4];
    const int w = t >> 6, lane = t & 63;
    if (lane == 0) p[w] = r;
    __syncthreads();
    if (t < 2) rs1[(blockIdx.x << 1) + t] = p[t * 2] + p[t * 2 + 1];
}

// ---------------------------------------------------------------------------
extern "C" void kernel_launch(void* const* d_in, const int* in_sizes, int n_in,
                              void* d_out, int out_size, void* d_ws, size_t ws_size,
                              hipStream_t stream) {
    const float* x       = (const float*)d_in[0];
    const float* W_emb   = (const float*)d_in[1];
    const float* b_emb   = (const float*)d_in[2];
    const float* W_pos1  = (const float*)d_in[3];
    const float* b_pos1  = (const float*)d_in[4];
    const float* W_red   = (const float*)d_in[5];
    const float* b_red   = (const float*)d_in[6];
    const float* W_pos2  = (const float*)d_in[7];
    const float* b_pos2  = (const float*)d_in[8];
    const float* W_red2  = (const float*)d_in[9];
    const float* b_red2  = (const float*)d_in[10];
    const float* W_pos3  = (const float*)d_in[11];
    const float* b_pos3  = (const float*)d_in[12];
    const float* W_down2 = (const float*)d_in[13];
    const float* b_down2 = (const float*)d_in[14];
    const float* W_flat  = (const float*)d_in[15];
    const float* b_flat  = (const float*)d_in[16];
    const float* W_d1    = (const float*)d_in[17];
    const float* b_d1    = (const float*)d_in[18];
    const float* W_d2    = (const float*)d_in[19];
    const float* b_d2    = (const float*)d_in[20];
    const float* W_d3    = (const float*)d_in[21];
    const float* b_d3    = (const float*)d_in[22];
    const float* W_p1    = (const float*)d_in[23];
    const float* b_p1    = (const float*)d_in[24];
    const float* W_p2    = (const float*)d_in[25];
    const float* b_p2    = (const float*)d_in[26];
    float* out = (float*)d_out;
    float* ws  = (float*)d_ws;

    size_t o = 0;
    auto alloc = [&](size_t n) { size_t p = o; o += (n + 63) & ~(size_t)63; return p; };
    const size_t oP1 = alloc(128 * 256);
    const size_t oP2 = alloc(128 * 512);
    const size_t oP3 = alloc(128 * 1280);
    const size_t oQ1 = alloc(128 * 128);
    const size_t oQ2 = alloc(128 * 256);
    const size_t oQ3 = alloc(128 * 640);
    const size_t oBC = alloc(32000);
    const size_t oH1 = alloc(2048 * 128);
    const size_t oRS1 = alloc(2048);
    const size_t oRS2 = alloc(2048);
    const size_t oH2 = alloc(2048 * 256);
    const size_t oH3 = alloc(2048 * 640);
    const size_t oH4 = alloc(2048 * 512);
    const size_t oH5 = alloc(16 * 512);
    const size_t oH6c = alloc(16 * 1024);    // h6 at stride 1024 (cols 0..511)
    const size_t oCat = alloc(16 * 1024);    // [h68 | h7] concat, stride 1024
    const size_t oM1 = alloc(16 * 32768);
    const size_t oM2 = alloc(16 * 163840);
    const size_t oWembT = alloc(2048000);    // bf16 buffers sized in floats
    const size_t oWd2T  = alloc(163840);
    const size_t oQ1T   = alloc(16384);
    const size_t oQ2T   = alloc(65536);
    const size_t oQ3T   = alloc(409600);
    const size_t oRegA = alloc(40u * 262144); // partials: GEMM1(40) / Wflat(256x8192) / proj(4x512000)
    const size_t oPartG1 = oRegA, oPartF = oRegA, oPartP = oRegA;
    (void)ws_size; (void)in_sizes; (void)n_in; (void)out_size;

    __bf16* WembT = (__bf16*)(ws + oWembT);
    __bf16* Wd2T  = (__bf16*)(ws + oWd2T);
    __bf16* Q1T   = (__bf16*)(ws + oQ1T);
    __bf16* Q2T   = (__bf16*)(ws + oQ2T);
    __bf16* Q3T   = (__bf16*)(ws + oQ3T);

    dim3 blk(256);

    // 1. prep: transposes + pos encodings + combined bias + rs2 zero
    prep_kernel<<<dim3(6437), blk, 0, stream>>>(
        ws + oP1, ws + oP2, ws + oP3, b_p1, b_p2, ws + oBC, ws + oRS2,
        W_emb, WembT, W_down2, Wd2T, W_pos1, Q1T, W_pos2, Q2T, W_pos3, Q3T);
    // 2. mega1: GEMM1 partials (ksplit=40, 5 blocks/CU) + Q1 + Q2 + Q3
    mega1_kernel<<<dim3(1296), blk, 0, stream>>>(
        x, WembT, ws + oPartG1,
        ws + oP1, Q1T, ws + oQ1, b_pos1,
        ws + oP2, Q2T, ws + oQ2, b_pos2,
        ws + oP3, Q3T, ws + oQ3, b_pos3);
    // 3. h1 = relu(sum + b_emb) + Q1 ; rs1 = rowsum(h1)
    reduce_rs_kernel<<<dim3(1024), blk, 0, stream>>>(ws + oPartG1, ws + oH1,
                                                     b_emb, ws + oQ1, ws + oRS1, 40);
    // 4. M1 = rs1(16x128) @ W_red viewed (128 x 32768)
    gemm_v2<1><<<dim3(256, 1, 1), blk, 0, stream>>>(ws + oRS1, W_red, nullptr,
        ws + oM1, nullptr, nullptr, nullptr,
        16, 32768, 128, 128, 32768, 32768, 1 << 30, 0, 0, 0, 1, 128, 0);
    // 5. h2 = relu(h1[b] @ M1[b] + b_red) + Q2 ; rs2 += rowsums (atomic)
    gemm_v2<1><<<dim3(2, 2, 16), blk, 0, stream>>>(ws + oH1, ws + oM1, nullptr,
        ws + oH2, b_red, ws + oQ2, ws + oRS2,
        128, 256, 128, 128, 256, 256, 1 << 30, 16384, 32768, 32768, 1, 128, 1);
    // 6. M2 = rs2(16x128) @ W_red2 viewed (128 x 163840)
    gemm_v2<1><<<dim3(1280, 1, 1), blk, 0, stream>>>(ws + oRS2, W_red2, nullptr,
        ws + oM2, nullptr, nullptr, nullptr,
        16, 163840, 128, 128, 163840, 163840, 1 << 30, 0, 0, 0, 1, 128, 0);
    // 7. h3 = relu(h2[b] @ M2[b] + b_red2) + Q3
    gemm_v2<1><<<dim3(5, 2, 16), blk, 0, stream>>>(ws + oH2, ws + oM2, nullptr,
        ws + oH3, b_red2, ws + oQ3, nullptr,
        128, 640, 256, 256, 640, 640, 1 << 30, 32768, 163840, 81920, 1, 256, 1);
    // 8. h4 = relu(h3 @ W_down2 + b_down2)
    gemm_v2<0><<<dim3(4, 32, 1), blk, 0, stream>>>(ws + oH3, Wd2T, nullptr,
        ws + oH4, b_down2, nullptr, nullptr,
        2048, 512, 640, 640, 640, 512, 1 << 30, 0, 0, 0, 1, 640, 1);
    // 9. h5 partials = h4 viewed (16x65536) @ W_flat, split-K 256 (4 blocks/CU)
    gemm_v2<1><<<dim3(4, 1, 256), blk, 0, stream>>>(ws + oH4, W_flat, nullptr,
        ws + oPartF, nullptr, nullptr, nullptr,
        16, 512, 65536, 65536, 512, 512, 1 << 30, 0, 0, 0, 256, 256, 0);
    // 10. h5 = relu(sum + b_flat)
    reduce_splitk<<<dim3(32), blk, 0, stream>>>(ws + oPartF, ws + oH5, b_flat,
                                                8192, 512, 256, 1);
    // 11-13. dense chain into stride-1024 concat layout
    gemm_v2<1><<<dim3(4, 1, 1), blk, 0, stream>>>(ws + oH5, W_d1, nullptr,
        ws + oH6c, b_d1, nullptr, nullptr,
        16, 512, 512, 512, 512, 1024, 1 << 30, 0, 0, 0, 1, 512, 1);
    gemm_v2<1><<<dim3(4, 1, 1), blk, 0, stream>>>(ws + oH6c, W_d2, nullptr,
        ws + oCat + 512, b_d2, nullptr, nullptr,
        16, 512, 512, 1024, 512, 1024, 1 << 30, 0, 0, 0, 1, 512, 1);
    gemm_v2<1><<<dim3(4, 1, 1), blk, 0, stream>>>(ws + oCat + 512, W_d3, nullptr,
        ws + oCat, b_d3, ws + oH6c, nullptr,
        16, 512, 512, 1024, 512, 1024, 1 << 30, 0, 0, 0, 1, 512, 1);
    // 14. proj partials = [h68|h7](16x1024) @ [W_p1;W_p2], split-K 4 (4/CU)
    gemm_v2<1><<<dim3(250, 1, 4), blk, 0, stream>>>(ws + oCat, W_p1, W_p2,
        ws + oPartP, nullptr, nullptr, nullptr,
        16, 32000, 1024, 1024, 32000, 32000, 512, 0, 0, 0, 4, 256, 0);
    // 15. out = sum partials + (2*b_p1 + b_p2)
    reduce_splitk<<<dim3(2000), blk, 0, stream>>>(ws + oPartP, out, ws + oBC,
                                                  512000, 32000, 4, 0);
}

// Round 13
// 373.079 us; speedup vs baseline: 1.1402x; 1.0723x over previous
//
#include <hip/hip_runtime.h>

typedef float  f4   __attribute__((ext_vector_type(4)));
typedef __bf16 bf8_t __attribute__((ext_vector_type(8)));
typedef __bf16 bf4_t __attribute__((ext_vector_type(4)));

__device__ __forceinline__ void glds16(const void* g, void* l) {
    __builtin_amdgcn_global_load_lds(
        (const __attribute__((address_space(1))) void*)g,
        (__attribute__((address_space(3))) void*)l, 16, 0, 0);
}

// ---------------------------------------------------------------------------
// prep: weight transposes (blocks 0..5279) + pos encodings / combined bias /
// rs2 zero (blocks 5280..6436).
// ---------------------------------------------------------------------------
__global__ __launch_bounds__(256)
void prep_kernel(float* __restrict__ P1, float* __restrict__ P2,
                 float* __restrict__ P3,
                 const float* __restrict__ bp1, const float* __restrict__ bp2,
                 float* __restrict__ bc, float* __restrict__ rs2,
                 const float* __restrict__ Wemb, __bf16* __restrict__ WembT,
                 const float* __restrict__ Wd2, __bf16* __restrict__ Wd2T,
                 const float* __restrict__ Wq1, __bf16* __restrict__ Wq1T,
                 const float* __restrict__ Wq2, __bf16* __restrict__ Wq2T,
                 const float* __restrict__ Wq3, __bf16* __restrict__ Wq3T) {
    const int bid = blockIdx.x;
    const int t = threadIdx.x;
    if (bid < 5280) {
        const float* src; __bf16* dst; int CN, RK, tn, local;
        if (bid < 4000)      { src = Wemb; dst = WembT; RK = 32000; CN = 128; tn = 4;  local = bid; }
        else if (bid < 4320) { src = Wd2;  dst = Wd2T;  RK = 640;   CN = 512; tn = 16; local = bid - 4000; }
        else if (bid < 4352) { src = Wq1;  dst = Wq1T;  RK = 256;   CN = 128; tn = 4;  local = bid - 4320; }
        else if (bid < 4480) { src = Wq2;  dst = Wq2T;  RK = 512;   CN = 256; tn = 8;  local = bid - 4352; }
        else                 { src = Wq3;  dst = Wq3T;  RK = 1280;  CN = 640; tn = 20; local = bid - 4480; }
        const int kt = local / tn, ntl = local - kt * tn;
        const int k0 = kt * 32, n0 = ntl * 32;
        __shared__ float tile[32][33];
        const int r = t >> 3, c4 = (t & 7) * 4;
        const f4 v = *(const f4*)(src + (long)(k0 + r) * CN + n0 + c4);
        tile[r][c4] = v[0]; tile[r][c4 + 1] = v[1];
        tile[r][c4 + 2] = v[2]; tile[r][c4 + 3] = v[3];
        __syncthreads();
        bf4_t o2;
        o2[0] = (__bf16)tile[c4][r];     o2[1] = (__bf16)tile[c4 + 1][r];
        o2[2] = (__bf16)tile[c4 + 2][r]; o2[3] = (__bf16)tile[c4 + 3][r];
        *(bf4_t*)(dst + (long)(n0 + r) * RK + k0 + c4) = o2;
        return;
    }
    int idx = (bid - 5280) * 256 + t;
    const int n1 = 128 * 256, n2 = 128 * 512;      // P3: 128*1280
    const int nP = 262144;
    if (idx < nP) {
        float* P; int d, local;
        if (idx < n1)           { P = P1; d = 256;  local = idx; }
        else if (idx < n1 + n2) { P = P2; d = 512;  local = idx - n1; }
        else                    { P = P3; d = 1280; local = idx - n1 - n2; }
        int s = local / d;
        int k = local - s * d;
        int i = k >> 1;
        float ang = (float)s * powf(10000.0f, (-2.0f * (float)i) / (float)d);
        P[local] = (k & 1) ? cosf(ang) : sinf(ang);
    } else if (idx < nP + 32000) {
        int j = idx - nP;
        bc[j] = 2.f * bp1[j] + bp2[j];
    } else if (idx < nP + 32000 + 2048) {
        rs2[idx - nP - 32000] = 0.f;
    }
}

// ---------------------------------------------------------------------------
// Core MFMA GEMM device body — exact R6 proven loop:
//   STAGE(next buf) | COMPUTE(cur) | __syncthreads.
// ---------------------------------------------------------------------------
template<int BMODE>
__device__ __forceinline__ void gemm_dev(
    float* As0, float* As1, float* Bb0, float* Bb1,
    const float* __restrict__ A, const void* __restrict__ Bv,
    const void* __restrict__ B2v, float* __restrict__ C,
    const float* __restrict__ bias, const float* __restrict__ addsrc,
    float* __restrict__ rsum,
    int M, int N, int K, int lda, int ldb, int ldc, int kswitch,
    long sA, long sB, long sC, int ksplit, int kchunk, int relu,
    int bn, int bm, int bz) {

    const int t = threadIdx.x;
    const int batch = bz / ksplit;
    const int kz = bz - batch * ksplit;
    const int m0 = bm * 64, n0 = bn * 128;
    const int kb = kz * kchunk;
    const int ke = (kb + kchunk < K) ? (kb + kchunk) : K;
    const int nit = (ke - kb + 31) >> 5;

    const int lane = t & 63;
    const int w = t >> 6;
    const int wm = w >> 1, wn = w & 1;
    const int fr = lane & 15;
    const int fq = (lane >> 4) * 8;

    f4 acc[2][4];
#pragma unroll
    for (int mt = 0; mt < 2; ++mt)
#pragma unroll
        for (int nt = 0; nt < 4; ++nt) acc[mt][nt] = (f4){0.f, 0.f, 0.f, 0.f};

    const float* Ab = A + (long)batch * sA;
    const int mvalid = M - m0;

    const int ra = t >> 3;
    const int ja = (t & 7) ^ (ra & 7);
    const float* aS0 = Ab + (long)(m0 + ra) * lda + 4 * ja;
    const float* aS1 = aS0 + 32L * lda;

    const __bf16* bTS0 = nullptr; const __bf16* bTS1 = nullptr;
    const float* bNS0 = nullptr; const float* bNS2 = nullptr;
    if constexpr (BMODE == 0) {
        const __bf16* BT = (const __bf16*)Bv + (long)batch * sB;
        const int nb = t >> 2;
        const int fb = (nb & 3) ^ ((nb >> 2) & 3);
        const int jb = (t & 3) ^ fb;
        bTS0 = BT + (long)(n0 + nb) * ldb + 8 * jb;
        bTS1 = bTS0 + 64L * ldb;
    } else {
        const float* Bn = (const float*)Bv + (long)batch * sB;
        bNS0 = Bn + (long)(t >> 5) * ldb + n0 + (t & 31) * 4;
        const float* Bn2 = (const float*)(B2v ? B2v : Bv);
        bNS2 = Bn2 + (long)(t >> 5) * ldb + n0 + (t & 31) * 4;
    }

    auto STAGE = [&](float* Ad, float* Bd, int k0) {
        if (ra < mvalid)      glds16(aS0 + k0, Ad + 4 * t);
        if (ra + 32 < mvalid) glds16(aS1 + k0, Ad + 1024 + 4 * t);
        if constexpr (BMODE == 0) {
            glds16(bTS0 + k0, Bd + 4 * t);
            glds16(bTS1 + k0, Bd + 1024 + 4 * t);
        } else {
            const float* bp = (k0 < kswitch) ? (bNS0 + (long)k0 * ldb)
                                             : (bNS2 + (long)(k0 - kswitch) * ldb);
            glds16(bp,             Bd + 4 * t);
            glds16(bp + 8L * ldb,  Bd + 1024 + 4 * t);
            glds16(bp + 16L * ldb, Bd + 2048 + 4 * t);
            glds16(bp + 24L * ldb, Bd + 3072 + 4 * t);
        }
    };

    // frag-read offsets (constant across K)
    const int R0 = wm * 32 + fr, R1 = R0 + 16;
    const int jq = (lane >> 4) * 2;
    const int x7 = R0 & 7;
    const int aO00 = R0 * 8 + (jq ^ x7);
    const int aO01 = R0 * 8 + ((jq + 1) ^ x7);
    const int aO10 = R1 * 8 + (jq ^ x7);
    const int aO11 = R1 * 8 + ((jq + 1) ^ x7);
    int bOf[4];
    if constexpr (BMODE == 0) {
        const int fbc = (fr & 3) ^ ((fr >> 2) & 3);
        const int jb2 = (lane >> 4) ^ fbc;
#pragma unroll
        for (int nt = 0; nt < 4; ++nt)
            bOf[nt] = ((wn * 64 + nt * 16 + fr) * 4 + jb2) * 8;  // bf16 idx
    } else {
#pragma unroll
        for (int nt = 0; nt < 4; ++nt)
            bOf[nt] = wn * 64 + nt * 16 + fr;                    // col idx
    }

    STAGE(As0, Bb0, kb);
    __syncthreads();
    int cur = 0;
    for (int i = 0; i < nit; ++i) {
        const float* Ac = cur ? As1 : As0;
        const float* Bc = cur ? Bb1 : Bb0;
        if (i + 1 < nit) STAGE(cur ? As0 : As1, cur ? Bb0 : Bb1, kb + (i + 1) * 32);

        f4 x0 = *(const f4*)(Ac + aO00 * 4);
        f4 x1 = *(const f4*)(Ac + aO01 * 4);
        f4 x2 = *(const f4*)(Ac + aO10 * 4);
        f4 x3 = *(const f4*)(Ac + aO11 * 4);
        bf8_t af0, af1;
#pragma unroll
        for (int q = 0; q < 4; ++q) {
            af0[q] = (__bf16)x0[q]; af0[4 + q] = (__bf16)x1[q];
            af1[q] = (__bf16)x2[q]; af1[4 + q] = (__bf16)x3[q];
        }
#pragma unroll
        for (int nt = 0; nt < 4; ++nt) {
            bf8_t bv;
            if constexpr (BMODE == 0) {
                bv = *(const bf8_t*)((const __bf16*)Bc + bOf[nt]);
            } else {
                const float* bb = Bc + fq * 128 + bOf[nt];
#pragma unroll
                for (int d2 = 0; d2 < 8; ++d2) bv[d2] = (__bf16)bb[d2 * 128];
            }
            acc[0][nt] = __builtin_amdgcn_mfma_f32_16x16x32_bf16(af0, bv, acc[0][nt], 0, 0, 0);
            acc[1][nt] = __builtin_amdgcn_mfma_f32_16x16x32_bf16(af1, bv, acc[1][nt], 0, 0, 0);
        }
        __syncthreads();
        cur ^= 1;
    }

    float* Cp; long ldcp;
    const bool fin = (ksplit == 1);
    if (!fin) { Cp = C + (long)(batch * ksplit + kz) * M * N; ldcp = N; }
    else      { Cp = C + (long)batch * sC;                    ldcp = ldc; }

    const int rb = m0 + wm * 32 + (lane >> 4) * 4;
    const int cb_ = n0 + wn * 64 + fr;
    float rowpart[2][4] = {{0.f,0.f,0.f,0.f},{0.f,0.f,0.f,0.f}};
#pragma unroll
    for (int mt = 0; mt < 2; ++mt) {
#pragma unroll
        for (int nt = 0; nt < 4; ++nt) {
            const int c = cb_ + nt * 16;
            const float bvl = (fin && bias) ? bias[c] : 0.f;
#pragma unroll
            for (int v = 0; v < 4; ++v) {
                const int r = rb + mt * 16 + v;
                if (r < M) {
                    float val = acc[mt][nt][v] + bvl;
                    if (fin && relu) val = fmaxf(val, 0.f);
                    if (fin && addsrc) val += addsrc[(long)r * ldcp + c];
                    Cp[(long)r * ldcp + c] = val;
                    rowpart[mt][v] += val;
                }
            }
        }
    }
    if (rsum) {
#pragma unroll
        for (int mt = 0; mt < 2; ++mt) {
#pragma unroll
            for (int v = 0; v < 4; ++v) {
                float s = rowpart[mt][v];
                s += __shfl_xor(s, 1); s += __shfl_xor(s, 2);
                s += __shfl_xor(s, 4); s += __shfl_xor(s, 8);
                const int r = rb + mt * 16 + v;
                if (fr == 0 && r < M) atomicAdd(&rsum[(long)bz * M + r], s);
            }
        }
    }
}

// ---------------------------------------------------------------------------
// GEMM1 with 128x128 tile: 4 waves x 32 rows, acc[2][8], 64 MFMA/iter.
// Same 2-phase loop and swizzle algebra; A staged via 4 glds16 issues
// (rows ra, ra+32, ra+64, ra+96; (row&7) invariant across issues).
// ksplit=48, kchunk=672 (last slice 416). Partials to part[kz*262144+...].
// ---------------------------------------------------------------------------
__device__ __forceinline__ void gemm1_t128(
    float* As0, float* As1, float* Bb0, float* Bb1,
    const float* __restrict__ x, const __bf16* __restrict__ WembT,
    float* __restrict__ part, int bm, int kz) {
    const int t = threadIdx.x;
    const int lane = t & 63;
    const int w = t >> 6;                 // wave owns rows w*32 .. w*32+31
    const int fr = lane & 15;
    const int m0 = bm * 128;
    const int kb = kz * 672;
    const int ke = (kb + 672 < 32000) ? kb + 672 : 32000;
    const int nit = (ke - kb) >> 5;

    f4 acc[2][8];
#pragma unroll
    for (int mt = 0; mt < 2; ++mt)
#pragma unroll
        for (int nt = 0; nt < 8; ++nt) acc[mt][nt] = (f4){0.f, 0.f, 0.f, 0.f};

    const int ra = t >> 3;
    const int ja = (t & 7) ^ (ra & 7);
    const float* aS = x + (long)(m0 + ra) * 32000 + 4 * ja;

    const int nb = t >> 2;
    const int fb = (nb & 3) ^ ((nb >> 2) & 3);
    const int jb = (t & 3) ^ fb;
    const __bf16* bTS0 = WembT + (long)nb * 32000 + 8 * jb;
    const __bf16* bTS1 = bTS0 + 64L * 32000;

    auto STAGE = [&](float* Ad, float* Bd, int k0) {
        glds16(aS + k0,               Ad + 4 * t);
        glds16(aS + 32L * 32000 + k0, Ad + 1024 + 4 * t);
        glds16(aS + 64L * 32000 + k0, Ad + 2048 + 4 * t);
        glds16(aS + 96L * 32000 + k0, Ad + 3072 + 4 * t);
        glds16(bTS0 + k0, Bd + 4 * t);
        glds16(bTS1 + k0, Bd + 1024 + 4 * t);
    };

    const int R0 = w * 32 + fr, R1 = R0 + 16;
    const int jq = (lane >> 4) * 2;
    const int x7 = R0 & 7;
    const int aO00 = R0 * 8 + (jq ^ x7);
    const int aO01 = R0 * 8 + ((jq + 1) ^ x7);
    const int aO10 = R1 * 8 + (jq ^ x7);
    const int aO11 = R1 * 8 + ((jq + 1) ^ x7);
    const int fbc = (fr & 3) ^ ((fr >> 2) & 3);
    const int jb2 = (lane >> 4) ^ fbc;
    int bOf[8];
#pragma unroll
    for (int nt = 0; nt < 8; ++nt)
        bOf[nt] = ((nt * 16 + fr) * 4 + jb2) * 8;    // bf16 idx

    STAGE(As0, Bb0, kb);
    __syncthreads();
    int cur = 0;
    for (int i = 0; i < nit; ++i) {
        const float* Ac = cur ? As1 : As0;
        const float* Bc = cur ? Bb1 : Bb0;
        if (i + 1 < nit) STAGE(cur ? As0 : As1, cur ? Bb0 : Bb1, kb + (i + 1) * 32);

        f4 x0 = *(const f4*)(Ac + aO00 * 4);
        f4 x1 = *(const f4*)(Ac + aO01 * 4);
        f4 x2 = *(const f4*)(Ac + aO10 * 4);
        f4 x3 = *(const f4*)(Ac + aO11 * 4);
        bf8_t af0, af1;
#pragma unroll
        for (int q = 0; q < 4; ++q) {
            af0[q] = (__bf16)x0[q]; af0[4 + q] = (__bf16)x1[q];
            af1[q] = (__bf16)x2[q]; af1[4 + q] = (__bf16)x3[q];
        }
#pragma unroll
        for (int nt = 0; nt < 8; ++nt) {
            bf8_t bv = *(const bf8_t*)((const __bf16*)Bc + bOf[nt]);
            acc[0][nt] = __builtin_amdgcn_mfma_f32_16x16x32_bf16(af0, bv, acc[0][nt], 0, 0, 0);
            acc[1][nt] = __builtin_amdgcn_mfma_f32_16x16x32_bf16(af1, bv, acc[1][nt], 0, 0, 0);
        }
        __syncthreads();
        cur ^= 1;
    }

    float* Cp = part + (long)kz * 262144;
    const int rb = m0 + w * 32 + (lane >> 4) * 4;
#pragma unroll
    for (int mt = 0; mt < 2; ++mt)
#pragma unroll
        for (int nt = 0; nt < 8; ++nt)
#pragma unroll
            for (int v = 0; v < 4; ++v)
                Cp[(long)(rb + mt * 16 + v) * 128 + nt * 16 + fr] = acc[mt][nt][v];
}

// Generic launch wrapper
template<int BMODE>
__global__ __launch_bounds__(256)
void gemm_v2(const float* A, const void* Bv, const void* B2v, float* C,
             const float* bias, const float* addsrc, float* rsum,
             int M, int N, int K, int lda, int ldb, int ldc, int kswitch,
             long sA, long sB, long sC, int ksplit, int kchunk, int relu) {
    __shared__ __align__(16) float AsF[2][2048];
    __shared__ __align__(16) float Bbuf[2][BMODE ? 4096 : 2048];
    gemm_dev<BMODE>(&AsF[0][0], &AsF[1][0], &Bbuf[0][0], &Bbuf[1][0],
                    A, Bv, B2v, C, bias, addsrc, rsum,
                    M, N, K, lda, ldb, ldc, kswitch, sA, sB, sC,
                    ksplit, kchunk, relu,
                    blockIdx.x, blockIdx.y, blockIdx.z);
}

// mega1: GEMM1 128x128 tile (768 blocks = 16 bm x 48 kz, XCD-grouped, 3/CU)
//        + Q1 (2) + Q2 (4) + Q3 (10).
__global__ __launch_bounds__(256)
void mega1_kernel(const float* __restrict__ x, const __bf16* __restrict__ WembT,
                  float* __restrict__ partG1,
                  const float* __restrict__ P1, const __bf16* __restrict__ Q1T,
                  float* __restrict__ Q1o, const float* __restrict__ bq1,
                  const float* __restrict__ P2, const __bf16* __restrict__ Q2T,
                  float* __restrict__ Q2o, const float* __restrict__ bq2,
                  const float* __restrict__ P3, const __bf16* __restrict__ Q3T,
                  float* __restrict__ Q3o, const float* __restrict__ bq3) {
    __shared__ __align__(16) float AsF[2][4096];   // 32 KB (A 128x32)
    __shared__ __align__(16) float Bbuf[2][2048];  // 16 KB -> 48 KB = 3/CU
    float* A0 = &AsF[0][0]; float* A1 = &AsF[1][0];
    float* B0 = &Bbuf[0][0]; float* B1 = &Bbuf[1][0];
    const int bid = blockIdx.x;
    if (bid < 768) {
        const int xc = bid & 7, j = bid >> 3;      // j in 0..95
        const int kz = xc + ((j >> 4) << 3);       // 48 kz, 6 per XCD
        const int bm = j & 15;
        gemm1_t128(A0, A1, B0, B1, x, WembT, partG1, bm, kz);
    } else if (bid < 770) {
        gemm_dev<0>(A0, A1, B0, B1, P1, Q1T, nullptr, Q1o,
                    bq1, nullptr, nullptr,
                    128, 128, 256, 256, 256, 128, 256,
                    0, 0, 0, 1, 256, 1, 0, bid - 768, 0);
    } else if (bid < 774) {
        const int l = bid - 770;
        gemm_dev<0>(A0, A1, B0, B1, P2, Q2T, nullptr, Q2o,
                    bq2, nullptr, nullptr,
                    128, 256, 512, 512, 512, 256, 512,
                    0, 0, 0, 1, 512, 1, l & 1, l >> 1, 0);
    } else {
        const int l = bid - 774;
        gemm_dev<0>(A0, A1, B0, B1, P3, Q3T, nullptr, Q3o,
                    bq3, nullptr, nullptr,
                    128, 640, 1280, 1280, 1280, 640, 1280,
                    0, 0, 0, 1, 1280, 1, l % 5, l / 5, 0);
    }
}

// out[idx] = [relu](sum_z part[z*MN+idx] + bias[idx%N])
__global__ __launch_bounds__(256)
void reduce_splitk(const float* __restrict__ part, float* __restrict__ outp,
                   const float* __restrict__ bias, int MN, int N, int ksplit,
                   int relu) {
    int idx = blockIdx.x * 256 + threadIdx.x;
    if (idx >= MN) return;
    float s = 0.f;
    for (int z = 0; z < ksplit; ++z) s += part[(long)z * MN + idx];
    if (bias) s += bias[idx % N];
    if (relu) s = fmaxf(s, 0.f);
    outp[idx] = s;
}

// GEMM1 reduce: h1 = relu(sum_z part + b_emb) + Q1; rs1 = rowsum(h1).
__global__ __launch_bounds__(256)
void reduce_rs_kernel(const float* __restrict__ part, float* __restrict__ h1,
                      const float* __restrict__ bias, const float* __restrict__ Q1,
                      float* __restrict__ rs1, int ksplit) {
    const int t = threadIdx.x;
    const int idx = blockIdx.x * 256 + t;
    float s = 0.f;
    for (int z = 0; z < ksplit; ++z) s += part[(long)z * 262144 + idx];
    s += bias[idx & 127];
    s = fmaxf(s, 0.f);
    s += Q1[idx & 16383];
    h1[idx] = s;
    float r = s;
    for (int off = 32; off > 0; off >>= 1) r += __shfl_down(r, off, 64);
    __shared__ float p[4];
    const int w = t >> 6, lane = t & 63;
    if (lane == 0) p[w] = r;
    __syncthreads();
    if (t < 2) rs1[(blockIdx.x << 1) + t] = p[t * 2] + p[t * 2 + 1];
}

// ---------------------------------------------------------------------------
extern "C" void kernel_launch(void* const* d_in, const int* in_sizes, int n_in,
                              void* d_out, int out_size, void* d_ws, size_t ws_size,
                              hipStream_t stream) {
    const float* x       = (const float*)d_in[0];
    const float* W_emb   = (const float*)d_in[1];
    const float* b_emb   = (const float*)d_in[2];
    const float* W_pos1  = (const float*)d_in[3];
    const float* b_pos1  = (const float*)d_in[4];
    const float* W_red   = (const float*)d_in[5];
    const float* b_red   = (const float*)d_in[6];
    const float* W_pos2  = (const float*)d_in[7];
    const float* b_pos2  = (const float*)d_in[8];
    const float* W_red2  = (const float*)d_in[9];
    const float* b_red2  = (const float*)d_in[10];
    const float* W_pos3  = (const float*)d_in[11];
    const float* b_pos3  = (const float*)d_in[12];
    const float* W_down2 = (const float*)d_in[13];
    const float* b_down2 = (const float*)d_in[14];
    const float* W_flat  = (const float*)d_in[15];
    const float* b_flat  = (const float*)d_in[16];
    const float* W_d1    = (const float*)d_in[17];
    const float* b_d1    = (const float*)d_in[18];
    const float* W_d2    = (const float*)d_in[19];
    const float* b_d2    = (const float*)d_in[20];
    const float* W_d3    = (const float*)d_in[21];
    const float* b_d3    = (const float*)d_in[22];
    const float* W_p1    = (const float*)d_in[23];
    const float* b_p1    = (const float*)d_in[24];
    const float* W_p2    = (const float*)d_in[25];
    const float* b_p2    = (const float*)d_in[26];
    float* out = (float*)d_out;
    float* ws  = (float*)d_ws;

    size_t o = 0;
    auto alloc = [&](size_t n) { size_t p = o; o += (n + 63) & ~(size_t)63; return p; };
    const size_t oP1 = alloc(128 * 256);
    const size_t oP2 = alloc(128 * 512);
    const size_t oP3 = alloc(128 * 1280);
    const size_t oQ1 = alloc(128 * 128);
    const size_t oQ2 = alloc(128 * 256);
    const size_t oQ3 = alloc(128 * 640);
    const size_t oBC = alloc(32000);
    const size_t oH1 = alloc(2048 * 128);
    const size_t oRS1 = alloc(2048);
    const size_t oRS2 = alloc(2048);
    const size_t oH2 = alloc(2048 * 256);
    const size_t oH3 = alloc(2048 * 640);
    const size_t oH4 = alloc(2048 * 512);
    const size_t oH5 = alloc(16 * 512);
    const size_t oH6c = alloc(16 * 1024);    // h6 at stride 1024 (cols 0..511)
    const size_t oCat = alloc(16 * 1024);    // [h68 | h7] concat, stride 1024
    const size_t oM1 = alloc(16 * 32768);
    const size_t oM2 = alloc(16 * 163840);
    const size_t oWembT = alloc(2048000);    // bf16 buffers sized in floats
    const size_t oWd2T  = alloc(163840);
    const size_t oQ1T   = alloc(16384);
    const size_t oQ2T   = alloc(65536);
    const size_t oQ3T   = alloc(409600);
    const size_t oRegA = alloc(48u * 262144); // partials: GEMM1(48) / W_flat(64x8192)
    const size_t oPartG1 = oRegA, oPartF = oRegA;
    (void)ws_size; (void)in_sizes; (void)n_in; (void)out_size;

    __bf16* WembT = (__bf16*)(ws + oWembT);
    __bf16* Wd2T  = (__bf16*)(ws + oWd2T);
    __bf16* Q1T   = (__bf16*)(ws + oQ1T);
    __bf16* Q2T   = (__bf16*)(ws + oQ2T);
    __bf16* Q3T   = (__bf16*)(ws + oQ3T);

    dim3 blk(256);

    // 1. prep: transposes + pos encodings + combined bias + rs2 zero
    prep_kernel<<<dim3(6437), blk, 0, stream>>>(
        ws + oP1, ws + oP2, ws + oP3, b_p1, b_p2, ws + oBC, ws + oRS2,
        W_emb, WembT, W_down2, Wd2T, W_pos1, Q1T, W_pos2, Q2T, W_pos3, Q3T);
    // 2. mega1: GEMM1 partials (128x128 tile, ksplit=48) + Q1 + Q2 + Q3
    mega1_kernel<<<dim3(784), blk, 0, stream>>>(
        x, WembT, ws + oPartG1,
        ws + oP1, Q1T, ws + oQ1, b_pos1,
        ws + oP2, Q2T, ws + oQ2, b_pos2,
        ws + oP3, Q3T, ws + oQ3, b_pos3);
    // 3. h1 = relu(sum + b_emb) + Q1 ; rs1 = rowsum(h1)
    reduce_rs_kernel<<<dim3(1024), blk, 0, stream>>>(ws + oPartG1, ws + oH1,
                                                     b_emb, ws + oQ1, ws + oRS1, 48);
    // 4. M1 = rs1(16x128) @ W_red viewed (128 x 32768)
    gemm_v2<1><<<dim3(256, 1, 1), blk, 0, stream>>>(ws + oRS1, W_red, nullptr,
        ws + oM1, nullptr, nullptr, nullptr,
        16, 32768, 128, 128, 32768, 32768, 1 << 30, 0, 0, 0, 1, 128, 0);
    // 5. h2 = relu(h1[b] @ M1[b] + b_red) + Q2 ; rs2 += rowsums (atomic)
    gemm_v2<1><<<dim3(2, 2, 16), blk, 0, stream>>>(ws + oH1, ws + oM1, nullptr,
        ws + oH2, b_red, ws + oQ2, ws + oRS2,
        128, 256, 128, 128, 256, 256, 1 << 30, 16384, 32768, 32768, 1, 128, 1);
    // 6. M2 = rs2(16x128) @ W_red2 viewed (128 x 163840)
    gemm_v2<1><<<dim3(1280, 1, 1), blk, 0, stream>>>(ws + oRS2, W_red2, nullptr,
        ws + oM2, nullptr, nullptr, nullptr,
        16, 163840, 128, 128, 163840, 163840, 1 << 30, 0, 0, 0, 1, 128, 0);
    // 7. h3 = relu(h2[b] @ M2[b] + b_red2) + Q3
    gemm_v2<1><<<dim3(5, 2, 16), blk, 0, stream>>>(ws + oH2, ws + oM2, nullptr,
        ws + oH3, b_red2, ws + oQ3, nullptr,
        128, 640, 256, 256, 640, 640, 1 << 30, 32768, 163840, 81920, 1, 256, 1);
    // 8. h4 = relu(h3 @ W_down2 + b_down2)
    gemm_v2<0><<<dim3(4, 32, 1), blk, 0, stream>>>(ws + oH3, Wd2T, nullptr,
        ws + oH4, b_down2, nullptr, nullptr,
        2048, 512, 640, 640, 640, 512, 1 << 30, 0, 0, 0, 1, 640, 1);
    // 9. h5 partials = h4 viewed (16x65536) @ W_flat, split-K 64
    gemm_v2<1><<<dim3(4, 1, 64), blk, 0, stream>>>(ws + oH4, W_flat, nullptr,
        ws + oPartF, nullptr, nullptr, nullptr,
        16, 512, 65536, 65536, 512, 512, 1 << 30, 0, 0, 0, 64, 1024, 0);
    // 10. h5 = relu(sum + b_flat)
    reduce_splitk<<<dim3(32), blk, 0, stream>>>(ws + oPartF, ws + oH5, b_flat,
                                                8192, 512, 64, 1);
    // 11-13. dense chain into stride-1024 concat layout
    gemm_v2<1><<<dim3(4, 1, 1), blk, 0, stream>>>(ws + oH5, W_d1, nullptr,
        ws + oH6c, b_d1, nullptr, nullptr,
        16, 512, 512, 512, 512, 1024, 1 << 30, 0, 0, 0, 1, 512, 1);
    gemm_v2<1><<<dim3(4, 1, 1), blk, 0, stream>>>(ws + oH6c, W_d2, nullptr,
        ws + oCat + 512, b_d2, nullptr, nullptr,
        16, 512, 512, 1024, 512, 1024, 1 << 30, 0, 0, 0, 1, 512, 1);
    gemm_v2<1><<<dim3(4, 1, 1), blk, 0, stream>>>(ws + oCat + 512, W_d3, nullptr,
        ws + oCat, b_d3, ws + oH6c, nullptr,
        16, 512, 512, 1024, 512, 1024, 1 << 30, 0, 0, 0, 1, 512, 1);
    // 14. out  = h68 @ W_p1 + (2*b_p1 + b_p2)   [cat cols 0..511]
    gemm_v2<1><<<dim3(250, 1, 1), blk, 0, stream>>>(ws + oCat, W_p1, nullptr,
        out, ws + oBC, nullptr, nullptr,
        16, 32000, 512, 1024, 32000, 32000, 1 << 30, 0, 0, 0, 1, 512, 0);
    // 15. out += h7 @ W_p2                      [cat cols 512..1023]
    gemm_v2<1><<<dim3(250, 1, 1), blk, 0, stream>>>(ws + oCat + 512, W_p2, nullptr,
        out, nullptr, out, nullptr,
        16, 32000, 512, 1024, 32000, 32000, 1 << 30, 0, 0, 0, 1, 512, 0);
}

// Round 14
// 363.281 us; speedup vs baseline: 1.1710x; 1.0270x over previous
//
#include <hip/hip_runtime.h>

typedef float  f4   __attribute__((ext_vector_type(4)));
typedef __bf16 bf8_t __attribute__((ext_vector_type(8)));
typedef __bf16 bf4_t __attribute__((ext_vector_type(4)));

__device__ __forceinline__ void glds16(const void* g, void* l) {
    __builtin_amdgcn_global_load_lds(
        (const __attribute__((address_space(1))) void*)g,
        (__attribute__((address_space(3))) void*)l, 16, 0, 0);
}

// ---------------------------------------------------------------------------
// prep: weight transposes (blocks 0..5279) + pos encodings / combined bias /
// rs2 zero (blocks 5280..6436).
// ---------------------------------------------------------------------------
__global__ __launch_bounds__(256)
void prep_kernel(float* __restrict__ P1, float* __restrict__ P2,
                 float* __restrict__ P3,
                 const float* __restrict__ bp1, const float* __restrict__ bp2,
                 float* __restrict__ bc, float* __restrict__ rs2,
                 const float* __restrict__ Wemb, __bf16* __restrict__ WembT,
                 const float* __restrict__ Wd2, __bf16* __restrict__ Wd2T,
                 const float* __restrict__ Wq1, __bf16* __restrict__ Wq1T,
                 const float* __restrict__ Wq2, __bf16* __restrict__ Wq2T,
                 const float* __restrict__ Wq3, __bf16* __restrict__ Wq3T) {
    const int bid = blockIdx.x;
    const int t = threadIdx.x;
    if (bid < 5280) {
        const float* src; __bf16* dst; int CN, RK, tn, local;
        if (bid < 4000)      { src = Wemb; dst = WembT; RK = 32000; CN = 128; tn = 4;  local = bid; }
        else if (bid < 4320) { src = Wd2;  dst = Wd2T;  RK = 640;   CN = 512; tn = 16; local = bid - 4000; }
        else if (bid < 4352) { src = Wq1;  dst = Wq1T;  RK = 256;   CN = 128; tn = 4;  local = bid - 4320; }
        else if (bid < 4480) { src = Wq2;  dst = Wq2T;  RK = 512;   CN = 256; tn = 8;  local = bid - 4352; }
        else                 { src = Wq3;  dst = Wq3T;  RK = 1280;  CN = 640; tn = 20; local = bid - 4480; }
        const int kt = local / tn, ntl = local - kt * tn;
        const int k0 = kt * 32, n0 = ntl * 32;
        __shared__ float tile[32][33];
        const int r = t >> 3, c4 = (t & 7) * 4;
        const f4 v = *(const f4*)(src + (long)(k0 + r) * CN + n0 + c4);
        tile[r][c4] = v[0]; tile[r][c4 + 1] = v[1];
        tile[r][c4 + 2] = v[2]; tile[r][c4 + 3] = v[3];
        __syncthreads();
        bf4_t o2;
        o2[0] = (__bf16)tile[c4][r];     o2[1] = (__bf16)tile[c4 + 1][r];
        o2[2] = (__bf16)tile[c4 + 2][r]; o2[3] = (__bf16)tile[c4 + 3][r];
        *(bf4_t*)(dst + (long)(n0 + r) * RK + k0 + c4) = o2;
        return;
    }
    int idx = (bid - 5280) * 256 + t;
    const int n1 = 128 * 256, n2 = 128 * 512;      // P3: 128*1280
    const int nP = 262144;
    if (idx < nP) {
        float* P; int d, local;
        if (idx < n1)           { P = P1; d = 256;  local = idx; }
        else if (idx < n1 + n2) { P = P2; d = 512;  local = idx - n1; }
        else                    { P = P3; d = 1280; local = idx - n1 - n2; }
        int s = local / d;
        int k = local - s * d;
        int i = k >> 1;
        float ang = (float)s * powf(10000.0f, (-2.0f * (float)i) / (float)d);
        P[local] = (k & 1) ? cosf(ang) : sinf(ang);
    } else if (idx < nP + 32000) {
        int j = idx - nP;
        bc[j] = 2.f * bp1[j] + bp2[j];
    } else if (idx < nP + 32000 + 2048) {
        rs2[idx - nP - 32000] = 0.f;
    }
}

// ---------------------------------------------------------------------------
// Core MFMA GEMM device body — exact R6 proven loop:
//   STAGE(next buf) | COMPUTE(cur) | __syncthreads.
// ---------------------------------------------------------------------------
template<int BMODE>
__device__ __forceinline__ void gemm_dev(
    float* As0, float* As1, float* Bb0, float* Bb1,
    const float* __restrict__ A, const void* __restrict__ Bv,
    const void* __restrict__ B2v, float* __restrict__ C,
    const float* __restrict__ bias, const float* __restrict__ addsrc,
    float* __restrict__ rsum,
    int M, int N, int K, int lda, int ldb, int ldc, int kswitch,
    long sA, long sB, long sC, int ksplit, int kchunk, int relu,
    int bn, int bm, int bz) {

    const int t = threadIdx.x;
    const int batch = bz / ksplit;
    const int kz = bz - batch * ksplit;
    const int m0 = bm * 64, n0 = bn * 128;
    const int kb = kz * kchunk;
    const int ke = (kb + kchunk < K) ? (kb + kchunk) : K;
    const int nit = (ke - kb + 31) >> 5;

    const int lane = t & 63;
    const int w = t >> 6;
    const int wm = w >> 1, wn = w & 1;
    const int fr = lane & 15;
    const int fq = (lane >> 4) * 8;

    f4 acc[2][4];
#pragma unroll
    for (int mt = 0; mt < 2; ++mt)
#pragma unroll
        for (int nt = 0; nt < 4; ++nt) acc[mt][nt] = (f4){0.f, 0.f, 0.f, 0.f};

    const float* Ab = A + (long)batch * sA;
    const int mvalid = M - m0;

    const int ra = t >> 3;
    const int ja = (t & 7) ^ (ra & 7);
    const float* aS0 = Ab + (long)(m0 + ra) * lda + 4 * ja;
    const float* aS1 = aS0 + 32L * lda;

    const __bf16* bTS0 = nullptr; const __bf16* bTS1 = nullptr;
    const float* bNS0 = nullptr; const float* bNS2 = nullptr;
    if constexpr (BMODE == 0) {
        const __bf16* BT = (const __bf16*)Bv + (long)batch * sB;
        const int nb = t >> 2;
        const int fb = (nb & 3) ^ ((nb >> 2) & 3);
        const int jb = (t & 3) ^ fb;
        bTS0 = BT + (long)(n0 + nb) * ldb + 8 * jb;
        bTS1 = bTS0 + 64L * ldb;
    } else {
        const float* Bn = (const float*)Bv + (long)batch * sB;
        bNS0 = Bn + (long)(t >> 5) * ldb + n0 + (t & 31) * 4;
        const float* Bn2 = (const float*)(B2v ? B2v : Bv);
        bNS2 = Bn2 + (long)(t >> 5) * ldb + n0 + (t & 31) * 4;
    }

    auto STAGE = [&](float* Ad, float* Bd, int k0) {
        if (ra < mvalid)      glds16(aS0 + k0, Ad + 4 * t);
        if (ra + 32 < mvalid) glds16(aS1 + k0, Ad + 1024 + 4 * t);
        if constexpr (BMODE == 0) {
            glds16(bTS0 + k0, Bd + 4 * t);
            glds16(bTS1 + k0, Bd + 1024 + 4 * t);
        } else {
            const float* bp = (k0 < kswitch) ? (bNS0 + (long)k0 * ldb)
                                             : (bNS2 + (long)(k0 - kswitch) * ldb);
            glds16(bp,             Bd + 4 * t);
            glds16(bp + 8L * ldb,  Bd + 1024 + 4 * t);
            glds16(bp + 16L * ldb, Bd + 2048 + 4 * t);
            glds16(bp + 24L * ldb, Bd + 3072 + 4 * t);
        }
    };

    // frag-read offsets (constant across K)
    const int R0 = wm * 32 + fr, R1 = R0 + 16;
    const int jq = (lane >> 4) * 2;
    const int x7 = R0 & 7;
    const int aO00 = R0 * 8 + (jq ^ x7);
    const int aO01 = R0 * 8 + ((jq + 1) ^ x7);
    const int aO10 = R1 * 8 + (jq ^ x7);
    const int aO11 = R1 * 8 + ((jq + 1) ^ x7);
    int bOf[4];
    if constexpr (BMODE == 0) {
        const int fbc = (fr & 3) ^ ((fr >> 2) & 3);
        const int jb2 = (lane >> 4) ^ fbc;
#pragma unroll
        for (int nt = 0; nt < 4; ++nt)
            bOf[nt] = ((wn * 64 + nt * 16 + fr) * 4 + jb2) * 8;  // bf16 idx
    } else {
#pragma unroll
        for (int nt = 0; nt < 4; ++nt)
            bOf[nt] = wn * 64 + nt * 16 + fr;                    // col idx
    }

    STAGE(As0, Bb0, kb);
    __syncthreads();
    int cur = 0;
    for (int i = 0; i < nit; ++i) {
        const float* Ac = cur ? As1 : As0;
        const float* Bc = cur ? Bb1 : Bb0;
        if (i + 1 < nit) STAGE(cur ? As0 : As1, cur ? Bb0 : Bb1, kb + (i + 1) * 32);

        f4 x0 = *(const f4*)(Ac + aO00 * 4);
        f4 x1 = *(const f4*)(Ac + aO01 * 4);
        f4 x2 = *(const f4*)(Ac + aO10 * 4);
        f4 x3 = *(const f4*)(Ac + aO11 * 4);
        bf8_t af0, af1;
#pragma unroll
        for (int q = 0; q < 4; ++q) {
            af0[q] = (__bf16)x0[q]; af0[4 + q] = (__bf16)x1[q];
            af1[q] = (__bf16)x2[q]; af1[4 + q] = (__bf16)x3[q];
        }
#pragma unroll
        for (int nt = 0; nt < 4; ++nt) {
            bf8_t bv;
            if constexpr (BMODE == 0) {
                bv = *(const bf8_t*)((const __bf16*)Bc + bOf[nt]);
            } else {
                const float* bb = Bc + fq * 128 + bOf[nt];
#pragma unroll
                for (int d2 = 0; d2 < 8; ++d2) bv[d2] = (__bf16)bb[d2 * 128];
            }
            acc[0][nt] = __builtin_amdgcn_mfma_f32_16x16x32_bf16(af0, bv, acc[0][nt], 0, 0, 0);
            acc[1][nt] = __builtin_amdgcn_mfma_f32_16x16x32_bf16(af1, bv, acc[1][nt], 0, 0, 0);
        }
        __syncthreads();
        cur ^= 1;
    }

    float* Cp; long ldcp;
    const bool fin = (ksplit == 1);
    if (!fin) { Cp = C + (long)(batch * ksplit + kz) * M * N; ldcp = N; }
    else      { Cp = C + (long)batch * sC;                    ldcp = ldc; }

    const int rb = m0 + wm * 32 + (lane >> 4) * 4;
    const int cb_ = n0 + wn * 64 + fr;
    float rowpart[2][4] = {{0.f,0.f,0.f,0.f},{0.f,0.f,0.f,0.f}};
#pragma unroll
    for (int mt = 0; mt < 2; ++mt) {
#pragma unroll
        for (int nt = 0; nt < 4; ++nt) {
            const int c = cb_ + nt * 16;
            const float bvl = (fin && bias) ? bias[c] : 0.f;
#pragma unroll
            for (int v = 0; v < 4; ++v) {
                const int r = rb + mt * 16 + v;
                if (r < M) {
                    float val = acc[mt][nt][v] + bvl;
                    if (fin && relu) val = fmaxf(val, 0.f);
                    if (fin && addsrc) val += addsrc[(long)r * ldcp + c];
                    Cp[(long)r * ldcp + c] = val;
                    rowpart[mt][v] += val;
                }
            }
        }
    }
    if (rsum) {
#pragma unroll
        for (int mt = 0; mt < 2; ++mt) {
#pragma unroll
            for (int v = 0; v < 4; ++v) {
                float s = rowpart[mt][v];
                s += __shfl_xor(s, 1); s += __shfl_xor(s, 2);
                s += __shfl_xor(s, 4); s += __shfl_xor(s, 8);
                const int r = rb + mt * 16 + v;
                if (fr == 0 && r < M) atomicAdd(&rsum[(long)bz * M + r], s);
            }
        }
    }
}

// ---------------------------------------------------------------------------
// GEMM1 with 128x128 tile: 4 waves x 32 rows, acc[2][8], 64 MFMA/iter.
// ksplit=48, kchunk=672 (last slice 416). Partials to part[kz*262144+...].
// ---------------------------------------------------------------------------
__device__ __forceinline__ void gemm1_t128(
    float* As0, float* As1, float* Bb0, float* Bb1,
    const float* __restrict__ x, const __bf16* __restrict__ WembT,
    float* __restrict__ part, int bm, int kz) {
    const int t = threadIdx.x;
    const int lane = t & 63;
    const int w = t >> 6;                 // wave owns rows w*32 .. w*32+31
    const int fr = lane & 15;
    const int m0 = bm * 128;
    const int kb = kz * 672;
    const int ke = (kb + 672 < 32000) ? kb + 672 : 32000;
    const int nit = (ke - kb) >> 5;

    f4 acc[2][8];
#pragma unroll
    for (int mt = 0; mt < 2; ++mt)
#pragma unroll
        for (int nt = 0; nt < 8; ++nt) acc[mt][nt] = (f4){0.f, 0.f, 0.f, 0.f};

    const int ra = t >> 3;
    const int ja = (t & 7) ^ (ra & 7);
    const float* aS = x + (long)(m0 + ra) * 32000 + 4 * ja;

    const int nb = t >> 2;
    const int fb = (nb & 3) ^ ((nb >> 2) & 3);
    const int jb = (t & 3) ^ fb;
    const __bf16* bTS0 = WembT + (long)nb * 32000 + 8 * jb;
    const __bf16* bTS1 = bTS0 + 64L * 32000;

    auto STAGE = [&](float* Ad, float* Bd, int k0) {
        glds16(aS + k0,               Ad + 4 * t);
        glds16(aS + 32L * 32000 + k0, Ad + 1024 + 4 * t);
        glds16(aS + 64L * 32000 + k0, Ad + 2048 + 4 * t);
        glds16(aS + 96L * 32000 + k0, Ad + 3072 + 4 * t);
        glds16(bTS0 + k0, Bd + 4 * t);
        glds16(bTS1 + k0, Bd + 1024 + 4 * t);
    };

    const int R0 = w * 32 + fr, R1 = R0 + 16;
    const int jq = (lane >> 4) * 2;
    const int x7 = R0 & 7;
    const int aO00 = R0 * 8 + (jq ^ x7);
    const int aO01 = R0 * 8 + ((jq + 1) ^ x7);
    const int aO10 = R1 * 8 + (jq ^ x7);
    const int aO11 = R1 * 8 + ((jq + 1) ^ x7);
    const int fbc = (fr & 3) ^ ((fr >> 2) & 3);
    const int jb2 = (lane >> 4) ^ fbc;
    int bOf[8];
#pragma unroll
    for (int nt = 0; nt < 8; ++nt)
        bOf[nt] = ((nt * 16 + fr) * 4 + jb2) * 8;    // bf16 idx

    STAGE(As0, Bb0, kb);
    __syncthreads();
    int cur = 0;
    for (int i = 0; i < nit; ++i) {
        const float* Ac = cur ? As1 : As0;
        const float* Bc = cur ? Bb1 : Bb0;
        if (i + 1 < nit) STAGE(cur ? As0 : As1, cur ? Bb0 : Bb1, kb + (i + 1) * 32);

        f4 x0 = *(const f4*)(Ac + aO00 * 4);
        f4 x1 = *(const f4*)(Ac + aO01 * 4);
        f4 x2 = *(const f4*)(Ac + aO10 * 4);
        f4 x3 = *(const f4*)(Ac + aO11 * 4);
        bf8_t af0, af1;
#pragma unroll
        for (int q = 0; q < 4; ++q) {
            af0[q] = (__bf16)x0[q]; af0[4 + q] = (__bf16)x1[q];
            af1[q] = (__bf16)x2[q]; af1[4 + q] = (__bf16)x3[q];
        }
#pragma unroll
        for (int nt = 0; nt < 8; ++nt) {
            bf8_t bv = *(const bf8_t*)((const __bf16*)Bc + bOf[nt]);
            acc[0][nt] = __builtin_amdgcn_mfma_f32_16x16x32_bf16(af0, bv, acc[0][nt], 0, 0, 0);
            acc[1][nt] = __builtin_amdgcn_mfma_f32_16x16x32_bf16(af1, bv, acc[1][nt], 0, 0, 0);
        }
        __syncthreads();
        cur ^= 1;
    }

    float* Cp = part + (long)kz * 262144;
    const int rb = m0 + w * 32 + (lane >> 4) * 4;
#pragma unroll
    for (int mt = 0; mt < 2; ++mt)
#pragma unroll
        for (int nt = 0; nt < 8; ++nt)
#pragma unroll
            for (int v = 0; v < 4; ++v)
                Cp[(long)(rb + mt * 16 + v) * 128 + nt * 16 + fr] = acc[mt][nt][v];
}

// Generic launch wrapper
template<int BMODE>
__global__ __launch_bounds__(256)
void gemm_v2(const float* A, const void* Bv, const void* B2v, float* C,
             const float* bias, const float* addsrc, float* rsum,
             int M, int N, int K, int lda, int ldb, int ldc, int kswitch,
             long sA, long sB, long sC, int ksplit, int kchunk, int relu) {
    __shared__ __align__(16) float AsF[2][2048];
    __shared__ __align__(16) float Bbuf[2][BMODE ? 4096 : 2048];
    gemm_dev<BMODE>(&AsF[0][0], &AsF[1][0], &Bbuf[0][0], &Bbuf[1][0],
                    A, Bv, B2v, C, bias, addsrc, rsum,
                    M, N, K, lda, ldb, ldc, kswitch, sA, sB, sC,
                    ksplit, kchunk, relu,
                    blockIdx.x, blockIdx.y, blockIdx.z);
}

// mega1: GEMM1 128x128 tile (768 blocks = 16 bm x 48 kz, XCD-grouped, 3/CU)
//        + Q1 (2) + Q2 (4) + Q3 (10).
__global__ __launch_bounds__(256)
void mega1_kernel(const float* __restrict__ x, const __bf16* __restrict__ WembT,
                  float* __restrict__ partG1,
                  const float* __restrict__ P1, const __bf16* __restrict__ Q1T,
                  float* __restrict__ Q1o, const float* __restrict__ bq1,
                  const float* __restrict__ P2, const __bf16* __restrict__ Q2T,
                  float* __restrict__ Q2o, const float* __restrict__ bq2,
                  const float* __restrict__ P3, const __bf16* __restrict__ Q3T,
                  float* __restrict__ Q3o, const float* __restrict__ bq3) {
    __shared__ __align__(16) float AsF[2][4096];   // 32 KB (A 128x32)
    __shared__ __align__(16) float Bbuf[2][2048];  // 16 KB -> 48 KB = 3/CU
    float* A0 = &AsF[0][0]; float* A1 = &AsF[1][0];
    float* B0 = &Bbuf[0][0]; float* B1 = &Bbuf[1][0];
    const int bid = blockIdx.x;
    if (bid < 768) {
        const int xc = bid & 7, j = bid >> 3;      // j in 0..95
        const int kz = xc + ((j >> 4) << 3);       // 48 kz, 6 per XCD
        const int bm = j & 15;
        gemm1_t128(A0, A1, B0, B1, x, WembT, partG1, bm, kz);
    } else if (bid < 770) {
        gemm_dev<0>(A0, A1, B0, B1, P1, Q1T, nullptr, Q1o,
                    bq1, nullptr, nullptr,
                    128, 128, 256, 256, 256, 128, 256,
                    0, 0, 0, 1, 256, 1, 0, bid - 768, 0);
    } else if (bid < 774) {
        const int l = bid - 770;
        gemm_dev<0>(A0, A1, B0, B1, P2, Q2T, nullptr, Q2o,
                    bq2, nullptr, nullptr,
                    128, 256, 512, 512, 512, 256, 512,
                    0, 0, 0, 1, 512, 1, l & 1, l >> 1, 0);
    } else {
        const int l = bid - 774;
        gemm_dev<0>(A0, A1, B0, B1, P3, Q3T, nullptr, Q3o,
                    bq3, nullptr, nullptr,
                    128, 640, 1280, 1280, 1280, 640, 1280,
                    0, 0, 0, 1, 1280, 1, l % 5, l / 5, 0);
    }
}

// out[idx] = [relu](sum_z part[z*MN+idx] + bias[idx%N])
__global__ __launch_bounds__(256)
void reduce_splitk(const float* __restrict__ part, float* __restrict__ outp,
                   const float* __restrict__ bias, int MN, int N, int ksplit,
                   int relu) {
    int idx = blockIdx.x * 256 + threadIdx.x;
    if (idx >= MN) return;
    float s = 0.f;
    for (int z = 0; z < ksplit; ++z) s += part[(long)z * MN + idx];
    if (bias) s += bias[idx % N];
    if (relu) s = fmaxf(s, 0.f);
    outp[idx] = s;
}

// GEMM1 reduce: h1 = relu(sum_z part + b_emb) + Q1; rs1 = rowsum(h1).
__global__ __launch_bounds__(256)
void reduce_rs_kernel(const float* __restrict__ part, float* __restrict__ h1,
                      const float* __restrict__ bias, const float* __restrict__ Q1,
                      float* __restrict__ rs1, int ksplit) {
    const int t = threadIdx.x;
    const int idx = blockIdx.x * 256 + t;
    float s = 0.f;
    for (int z = 0; z < ksplit; ++z) s += part[(long)z * 262144 + idx];
    s += bias[idx & 127];
    s = fmaxf(s, 0.f);
    s += Q1[idx & 16383];
    h1[idx] = s;
    float r = s;
    for (int off = 32; off > 0; off >>= 1) r += __shfl_down(r, off, 64);
    __shared__ float p[4];
    const int w = t >> 6, lane = t & 63;
    if (lane == 0) p[w] = r;
    __syncthreads();
    if (t < 2) rs1[(blockIdx.x << 1) + t] = p[t * 2] + p[t * 2 + 1];
}

// ---------------------------------------------------------------------------
extern "C" void kernel_launch(void* const* d_in, const int* in_sizes, int n_in,
                              void* d_out, int out_size, void* d_ws, size_t ws_size,
                              hipStream_t stream) {
    const float* x       = (const float*)d_in[0];
    const float* W_emb   = (const float*)d_in[1];
    const float* b_emb   = (const float*)d_in[2];
    const float* W_pos1  = (const float*)d_in[3];
    const float* b_pos1  = (const float*)d_in[4];
    const float* W_red   = (const float*)d_in[5];
    const float* b_red   = (const float*)d_in[6];
    const float* W_pos2  = (const float*)d_in[7];
    const float* b_pos2  = (const float*)d_in[8];
    const float* W_red2  = (const float*)d_in[9];
    const float* b_red2  = (const float*)d_in[10];
    const float* W_pos3  = (const float*)d_in[11];
    const float* b_pos3  = (const float*)d_in[12];
    const float* W_down2 = (const float*)d_in[13];
    const float* b_down2 = (const float*)d_in[14];
    const float* W_flat  = (const float*)d_in[15];
    const float* b_flat  = (const float*)d_in[16];
    const float* W_d1    = (const float*)d_in[17];
    const float* b_d1    = (const float*)d_in[18];
    const float* W_d2    = (const float*)d_in[19];
    const float* b_d2    = (const float*)d_in[20];
    const float* W_d3    = (const float*)d_in[21];
    const float* b_d3    = (const float*)d_in[22];
    const float* W_p1    = (const float*)d_in[23];
    const float* b_p1    = (const float*)d_in[24];
    const float* W_p2    = (const float*)d_in[25];
    const float* b_p2    = (const float*)d_in[26];
    float* out = (float*)d_out;
    float* ws  = (float*)d_ws;

    size_t o = 0;
    auto alloc = [&](size_t n) { size_t p = o; o += (n + 63) & ~(size_t)63; return p; };
    const size_t oP1 = alloc(128 * 256);
    const size_t oP2 = alloc(128 * 512);
    const size_t oP3 = alloc(128 * 1280);
    const size_t oQ1 = alloc(128 * 128);
    const size_t oQ2 = alloc(128 * 256);
    const size_t oQ3 = alloc(128 * 640);
    const size_t oBC = alloc(32000);
    const size_t oH1 = alloc(2048 * 128);
    const size_t oRS1 = alloc(2048);
    const size_t oRS2 = alloc(2048);
    const size_t oH2 = alloc(2048 * 256);
    const size_t oH3 = alloc(2048 * 640);
    const size_t oH4 = alloc(2048 * 512);
    const size_t oH5 = alloc(16 * 512);
    const size_t oH6c = alloc(16 * 1024);    // h6 at stride 1024 (cols 0..511)
    const size_t oCat = alloc(16 * 1024);    // [h68 | h7] concat, stride 1024
    const size_t oM1 = alloc(16 * 32768);
    const size_t oM2 = alloc(16 * 163840);
    const size_t oWembT = alloc(2048000);    // bf16 buffers sized in floats
    const size_t oWd2T  = alloc(163840);
    const size_t oQ1T   = alloc(16384);
    const size_t oQ2T   = alloc(65536);
    const size_t oQ3T   = alloc(409600);
    const size_t oRegA = alloc(48u * 262144); // partials: GEMM1(48) / W_flat(64x8192)
    const size_t oPartG1 = oRegA, oPartF = oRegA;
    (void)ws_size; (void)in_sizes; (void)n_in; (void)out_size;

    __bf16* WembT = (__bf16*)(ws + oWembT);
    __bf16* Wd2T  = (__bf16*)(ws + oWd2T);
    __bf16* Q1T   = (__bf16*)(ws + oQ1T);
    __bf16* Q2T   = (__bf16*)(ws + oQ2T);
    __bf16* Q3T   = (__bf16*)(ws + oQ3T);

    dim3 blk(256);

    // 1. prep: transposes + pos encodings + combined bias + rs2 zero
    prep_kernel<<<dim3(6437), blk, 0, stream>>>(
        ws + oP1, ws + oP2, ws + oP3, b_p1, b_p2, ws + oBC, ws + oRS2,
        W_emb, WembT, W_down2, Wd2T, W_pos1, Q1T, W_pos2, Q2T, W_pos3, Q3T);
    // 2. mega1: GEMM1 partials (128x128 tile, ksplit=48) + Q1 + Q2 + Q3
    mega1_kernel<<<dim3(784), blk, 0, stream>>>(
        x, WembT, ws + oPartG1,
        ws + oP1, Q1T, ws + oQ1, b_pos1,
        ws + oP2, Q2T, ws + oQ2, b_pos2,
        ws + oP3, Q3T, ws + oQ3, b_pos3);
    // 3. h1 = relu(sum + b_emb) + Q1 ; rs1 = rowsum(h1)
    reduce_rs_kernel<<<dim3(1024), blk, 0, stream>>>(ws + oPartG1, ws + oH1,
                                                     b_emb, ws + oQ1, ws + oRS1, 48);
    // 4. M1 = rs1(16x128) @ W_red viewed (128 x 32768)
    gemm_v2<1><<<dim3(256, 1, 1), blk, 0, stream>>>(ws + oRS1, W_red, nullptr,
        ws + oM1, nullptr, nullptr, nullptr,
        16, 32768, 128, 128, 32768, 32768, 1 << 30, 0, 0, 0, 1, 128, 0);
    // 5. h2 = relu(h1[b] @ M1[b] + b_red) + Q2 ; rs2 += rowsums (atomic)
    gemm_v2<1><<<dim3(2, 2, 16), blk, 0, stream>>>(ws + oH1, ws + oM1, nullptr,
        ws + oH2, b_red, ws + oQ2, ws + oRS2,
        128, 256, 128, 128, 256, 256, 1 << 30, 16384, 32768, 32768, 1, 128, 1);
    // 6. M2 = rs2(16x128) @ W_red2 viewed (128 x 163840)
    gemm_v2<1><<<dim3(1280, 1, 1), blk, 0, stream>>>(ws + oRS2, W_red2, nullptr,
        ws + oM2, nullptr, nullptr, nullptr,
        16, 163840, 128, 128, 163840, 163840, 1 << 30, 0, 0, 0, 1, 128, 0);
    // 7. h3 = relu(h2[b] @ M2[b] + b_red2) + Q3
    gemm_v2<1><<<dim3(5, 2, 16), blk, 0, stream>>>(ws + oH2, ws + oM2, nullptr,
        ws + oH3, b_red2, ws + oQ3, nullptr,
        128, 640, 256, 256, 640, 640, 1 << 30, 32768, 163840, 81920, 1, 256, 1);
    // 8. h4 = relu(h3 @ W_down2 + b_down2)
    gemm_v2<0><<<dim3(4, 32, 1), blk, 0, stream>>>(ws + oH3, Wd2T, nullptr,
        ws + oH4, b_down2, nullptr, nullptr,
        2048, 512, 640, 640, 640, 512, 1 << 30, 0, 0, 0, 1, 640, 1);
    // 9. h5 partials = h4 viewed (16x65536) @ W_flat, split-K 64
    gemm_v2<1><<<dim3(4, 1, 64), blk, 0, stream>>>(ws + oH4, W_flat, nullptr,
        ws + oPartF, nullptr, nullptr, nullptr,
        16, 512, 65536, 65536, 512, 512, 1 << 30, 0, 0, 0, 64, 1024, 0);
    // 10. h5 = relu(sum + b_flat)
    reduce_splitk<<<dim3(32), blk, 0, stream>>>(ws + oPartF, ws + oH5, b_flat,
                                                8192, 512, 64, 1);
    // 11-13. dense chain into stride-1024 concat layout
    gemm_v2<1><<<dim3(4, 1, 1), blk, 0, stream>>>(ws + oH5, W_d1, nullptr,
        ws + oH6c, b_d1, nullptr, nullptr,
        16, 512, 512, 512, 512, 1024, 1 << 30, 0, 0, 0, 1, 512, 1);
    gemm_v2<1><<<dim3(4, 1, 1), blk, 0, stream>>>(ws + oH6c, W_d2, nullptr,
        ws + oCat + 512, b_d2, nullptr, nullptr,
        16, 512, 512, 1024, 512, 1024, 1 << 30, 0, 0, 0, 1, 512, 1);
    gemm_v2<1><<<dim3(4, 1, 1), blk, 0, stream>>>(ws + oCat + 512, W_d3, nullptr,
        ws + oCat, b_d3, ws + oH6c, nullptr,
        16, 512, 512, 1024, 512, 1024, 1 << 30, 0, 0, 0, 1, 512, 1);
    // 14. out = [h68|h7](16x1024) @ [W_p1;W_p2](1024x32000) + (2*b_p1+b_p2)
    gemm_v2<1><<<dim3(250, 1, 1), blk, 0, stream>>>(ws + oCat, W_p1, W_p2,
        out, ws + oBC, nullptr, nullptr,
        16, 32000, 1024, 1024, 32000, 32000, 512, 0, 0, 0, 1, 1024, 0);
}